// Round 14
// baseline (398.854 us; speedup 1.0000x reference)
//
#include <hip/hip_runtime.h>
#include <hip/hip_bf16.h>
#include <math.h>

// N=10000, E=160000, C=16, C0=32, L=2, M=5, H=8, R_IN=32, R_HID=128, REQ=384

typedef short bf16x8 __attribute__((ext_vector_type(8)));
typedef float f32x4 __attribute__((ext_vector_type(4)));
typedef unsigned short ushort8v __attribute__((ext_vector_type(8)));

__device__ __forceinline__ float waveSum(float v) {
#pragma unroll
  for (int m = 1; m < 64; m <<= 1) v += __shfl_xor(v, m, 64);
  return v;
}
__device__ __forceinline__ unsigned encf(float f) {
  unsigned u = __float_as_uint(f);
  return (u & 0x80000000u) ? ~u : (u | 0x80000000u);
}
__device__ __forceinline__ float decf(unsigned u) {
  return (u & 0x80000000u) ? __uint_as_float(u & 0x7FFFFFFFu) : __uint_as_float(~u);
}
__device__ __forceinline__ unsigned short f2bu(float f) {
  __hip_bfloat16 h = __float2bfloat16(f);
  unsigned short u;
  __builtin_memcpy(&u, &h, 2);
  return u;
}
__device__ __forceinline__ float bu2f(unsigned u16) {
  unsigned x = u16 << 16;
  float f;
  __builtin_memcpy(&f, &x, 4);
  return f;
}

// ---------------------------------------------------------------------------
// Prep: transpose radial weights to bf16 [n][k] layout
// ---------------------------------------------------------------------------
__global__ __launch_bounds__(256) void prep_kernel(
    const float* __restrict__ W1, const float* __restrict__ W2,
    const float* __restrict__ W3,
    unsigned short* __restrict__ W1T, unsigned short* __restrict__ W2T,
    unsigned short* __restrict__ W3T) {
  int idx = blockIdx.x * 256 + threadIdx.x;
  if (idx < 128 * 32) {
    int n = idx >> 5, k = idx & 31;
    W1T[idx] = f2bu(W1[k * 128 + n]);
  }
  int i2 = idx - 128 * 32;
  if (i2 >= 0 && i2 < 128 * 128) {
    int n = i2 >> 7, k = i2 & 127;
    W2T[i2] = f2bu(W2[k * 128 + n]);
  }
  int i3 = idx - 128 * 32 - 128 * 128;
  if (i3 >= 0 && i3 < 384 * 128) {
    int n = i3 >> 7, k = i3 & 127;
    W3T[i3] = f2bu(W3[k * 384 + n]);
  }
}

// ---------------------------------------------------------------------------
// CSR build: count, scan (1 block), fill
// ---------------------------------------------------------------------------
__global__ __launch_bounds__(256) void count_kernel(const int* __restrict__ edge,
                                                    int* __restrict__ cnt, int E) {
  int e = blockIdx.x * 256 + threadIdx.x;
  if (e < E) atomicAdd(&cnt[edge[E + e]], 1);
}

__global__ __launch_bounds__(1024) void scan_kernel(const int* __restrict__ cnt,
                                                    int* __restrict__ rowstart, int N) {
  __shared__ int sp[1024];
  const int t = threadIdx.x;
  const int chunk = (N + 1023) >> 10;
  const int beg = t * chunk;
  const int end = min(beg + chunk, N);
  int s = 0;
  for (int i = beg; i < end; i++) s += cnt[i];
  sp[t] = s;
  __syncthreads();
  for (int off = 1; off < 1024; off <<= 1) {
    int tmp = (t >= off) ? sp[t - off] : 0;
    __syncthreads();
    sp[t] += tmp;
    __syncthreads();
  }
  int excl = sp[t] - s;
  int run = excl;
  for (int i = beg; i < end; i++) { rowstart[i] = run; run += cnt[i]; }
  if (t == 0) rowstart[N] = sp[1023];
}

__global__ __launch_bounds__(256) void fill_kernel(const int* __restrict__ edge,
                                                   const int* __restrict__ rowstart,
                                                   int* __restrict__ cursor,
                                                   int* __restrict__ csr, int E) {
  int e = blockIdx.x * 256 + threadIdx.x;
  if (e < E) {
    int d = edge[E + e];
    int p = atomicAdd(&cursor[d], 1);
    csr[rowstart[d] + p] = e;
  }
}

// ---------------------------------------------------------------------------
// Node prep: hoist channel-mix GEMMs to nodes.  Mixes stored bf16 padded
// [node][group][8] so edgeA's per-lane gather is one aligned 16B load.
// ---------------------------------------------------------------------------
__global__ __launch_bounds__(256) void nodeprep_kernel(
    const float* __restrict__ xt, const float* __restrict__ xt0,
    const float* __restrict__ xs, const float* __restrict__ xs0,
    const float* __restrict__ qW, const float* __restrict__ qW0,
    const float* __restrict__ qb0, const float* __restrict__ qng0,
    const float* __restrict__ kvW, const float* __restrict__ kvW0,
    const float* __restrict__ kvb0,
    unsigned short* __restrict__ qmixNb, float* __restrict__ q0N,
    unsigned short* __restrict__ kvmixNb, float* __restrict__ kv0N, int N) {
  __shared__ float sXT[4][160];
  __shared__ float sXS[4][160];
  __shared__ float sX0T[4][32];
  __shared__ float sX0S[4][32];
  const int tid = threadIdx.x, wv = tid >> 6, w = tid & 63;
  const int n = blockIdx.x * 4 + wv;
  if (n < N) {
    for (int i = w; i < 160; i += 64) {
      sXT[wv][i] = xt[(size_t)n * 160 + i];
      sXS[wv][i] = xs[(size_t)n * 160 + i];
    }
    if (w < 32) { sX0T[wv][w] = xt0[n * 32 + w]; sX0S[wv][w] = xs0[n * 32 + w]; }
  }
  __syncthreads();
  if (n >= N) return;
  for (int i = w; i < 160; i += 64) {
    int o = i / 10, lm = i % 10, l = lm / 5, m = lm % 5;
    const float4* wr = (const float4*)(qW + l * 256 + o * 16);
    float a = 0.f;
#pragma unroll
    for (int c4 = 0; c4 < 4; c4++) {
      float4 ww = wr[c4];
      a += ww.x * sXT[wv][(c4 * 4 + 0) * 10 + lm] + ww.y * sXT[wv][(c4 * 4 + 1) * 10 + lm]
         + ww.z * sXT[wv][(c4 * 4 + 2) * 10 + lm] + ww.w * sXT[wv][(c4 * 4 + 3) * 10 + lm];
    }
    qmixNb[(size_t)n * 256 + (o * 2 + l) * 8 + m] = f2bu(a);
  }
  for (int i = w; i < 320; i += 64) {
    int o = i / 10, lm = i % 10, l = lm / 5, m = lm % 5;
    const float4* wr = (const float4*)(kvW + l * 512 + o * 16);
    float a = 0.f;
#pragma unroll
    for (int c4 = 0; c4 < 4; c4++) {
      float4 ww = wr[c4];
      a += ww.x * sXS[wv][(c4 * 4 + 0) * 10 + lm] + ww.y * sXS[wv][(c4 * 4 + 1) * 10 + lm]
         + ww.z * sXS[wv][(c4 * 4 + 2) * 10 + lm] + ww.w * sXS[wv][(c4 * 4 + 3) * 10 + lm];
    }
    kvmixNb[(size_t)n * 512 + (o * 2 + l) * 8 + m] = f2bu(a);
  }
  {
    float a = 0.f;
    if (w < 32) {
      a = qb0[w];
      const float4* wr = (const float4*)(qW0 + w * 32);
#pragma unroll
      for (int c4 = 0; c4 < 8; c4++) {
        float4 ww = wr[c4];
        a += ww.x * sX0T[wv][c4 * 4] + ww.y * sX0T[wv][c4 * 4 + 1]
           + ww.z * sX0T[wv][c4 * 4 + 2] + ww.w * sX0T[wv][c4 * 4 + 3];
      }
    }
    float vv = (w < 32) ? a : 0.f;
    float s1 = waveSum(vv), s2 = waveSum(vv * vv);
    float mu = s1 / 32.f, var = s2 / 32.f - mu * mu;
    if (w < 32) q0N[(size_t)n * 32 + w] = (a - mu) * rsqrtf(var + 1e-5f) * qng0[w];
  }
  {
    float a = kvb0[w];
    const float4* wr = (const float4*)(kvW0 + w * 32);
#pragma unroll
    for (int c4 = 0; c4 < 8; c4++) {
      float4 ww = wr[c4];
      a += ww.x * sX0S[wv][c4 * 4] + ww.y * sX0S[wv][c4 * 4 + 1]
         + ww.z * sX0S[wv][c4 * 4 + 2] + ww.w * sX0S[wv][c4 * 4 + 3];
    }
    kv0N[(size_t)n * 64 + w] = a;
  }
}

// ---------------------------------------------------------------------------
// Fused radial MLP v6: same 64-edges/wave structure as v5 (verified), but
// 128-thread blocks with 32KB LDS -> 5 blocks/CU by LDS (10 waves/CU) and
// grid 1250 blocks (4.9/CU) instead of 625 (2.4/CU, occ 15.8% in r13).
// launch_bounds(128,3) leaves the 128-VGPR allocation untouched.
// ---------------------------------------------------------------------------
__global__ __launch_bounds__(128, 3) void radial_fused(
    const float* __restrict__ ef,
    const unsigned short* __restrict__ W1T, const unsigned short* __restrict__ W2T,
    const unsigned short* __restrict__ W3T,
    const float* __restrict__ b1, const float* __restrict__ g1, const float* __restrict__ be1,
    const float* __restrict__ b2, const float* __restrict__ g2, const float* __restrict__ be2,
    const float* __restrict__ b3,
    unsigned short* __restrict__ w_chunk, int e0) {
  __shared__ unsigned short sH[128 * 128];  // 32KB
  const int lane = threadIdx.x & 63;
  const int wid = threadIdx.x >> 6;  // 0..1
  const int colq = lane & 15, rowq = lane >> 4;
  int el[4], eg[4];
  unsigned swz[4], rbase[4];
#pragma unroll
  for (int t = 0; t < 4; t++) {
    el[t] = wid * 64 + t * 16 + colq;
    eg[t] = blockIdx.x * 128 + el[t];
    swz[t] = (unsigned)(el[t] & 7) << 4;
    rbase[t] = (unsigned)el[t] * 256;
  }
  char* sB = (char*)sH;
  f32x4 zz = {0.f, 0.f, 0.f, 0.f};

  // ---- layer 1: 32 -> 128 ----
  bf16x8 bfr[4];
#pragma unroll
  for (int t = 0; t < 4; t++) {
    const float* p = ef + (size_t)(e0 + eg[t]) * 32 + rowq * 8;
    float4 a = *(const float4*)p, b = *(const float4*)(p + 4);
    bfr[t][0] = (short)f2bu(a.x); bfr[t][1] = (short)f2bu(a.y);
    bfr[t][2] = (short)f2bu(a.z); bfr[t][3] = (short)f2bu(a.w);
    bfr[t][4] = (short)f2bu(b.x); bfr[t][5] = (short)f2bu(b.y);
    bfr[t][6] = (short)f2bu(b.z); bfr[t][7] = (short)f2bu(b.w);
  }
  f32x4 acc[4][8];
#pragma unroll
  for (int jt = 0; jt < 8; jt++) {
    bf16x8 wl = *(const bf16x8*)(W1T + (jt * 16 + colq) * 32 + rowq * 8);
#pragma unroll
    for (int t = 0; t < 4; t++)
      acc[t][jt] = __builtin_amdgcn_mfma_f32_16x16x32_bf16(wl, bfr[t], zz, 0, 0, 0);
  }
#pragma unroll
  for (int t = 0; t < 4; t++) {
    float s1 = 0.f, s2 = 0.f;
    float vv[8][4];
#pragma unroll
    for (int jt = 0; jt < 8; jt++) {
      float4 bb = *(const float4*)(b1 + jt * 16 + rowq * 4);
#pragma unroll
      for (int r = 0; r < 4; r++) {
        float v = acc[t][jt][r] + ((const float*)&bb)[r];
        vv[jt][r] = v; s1 += v; s2 += v * v;
      }
    }
    s1 += __shfl_xor(s1, 16, 64); s2 += __shfl_xor(s2, 16, 64);
    s1 += __shfl_xor(s1, 32, 64); s2 += __shfl_xor(s2, 32, 64);
    float mu = s1 * (1.f / 128.f);
    float rs = rsqrtf(s2 * (1.f / 128.f) - mu * mu + 1e-5f);
#pragma unroll
    for (int jt = 0; jt < 8; jt++) {
      float4 gg = *(const float4*)(g1 + jt * 16 + rowq * 4);
      float4 ee = *(const float4*)(be1 + jt * 16 + rowq * 4);
      ushort4 pk;
      unsigned short* pp = &pk.x;
#pragma unroll
      for (int r = 0; r < 4; r++) {
        float v = (vv[jt][r] - mu) * rs * ((const float*)&gg)[r] + ((const float*)&ee)[r];
        v = v / (1.f + __expf(-v));
        pp[r] = f2bu(v);
      }
      *(ushort4*)(sB + rbase[t] + (((unsigned)(jt * 32 + rowq * 8)) ^ swz[t])) = pk;
    }
  }

  // ---- layer 2: 128 -> 128 (ks-outer: one weight fragment feeds 4 MFMAs) ----
#pragma unroll
  for (int t = 0; t < 4; t++)
#pragma unroll
    for (int jt = 0; jt < 8; jt++) acc[t][jt] = zz;
#pragma unroll
  for (int ks = 0; ks < 4; ks++) {
    bf16x8 hh[4];
#pragma unroll
    for (int t = 0; t < 4; t++)
      hh[t] = *(const bf16x8*)(sB + rbase[t] + (((unsigned)(ks * 64 + rowq * 16)) ^ swz[t]));
#pragma unroll
    for (int jt = 0; jt < 8; jt++) {
      bf16x8 wf = *(const bf16x8*)(W2T + (size_t)(jt * 16 + colq) * 128 + ks * 32 + rowq * 8);
#pragma unroll
      for (int t = 0; t < 4; t++)
        acc[t][jt] = __builtin_amdgcn_mfma_f32_16x16x32_bf16(wf, hh[t], acc[t][jt], 0, 0, 0);
    }
  }
#pragma unroll
  for (int t = 0; t < 4; t++) {
    float s1 = 0.f, s2 = 0.f;
    float vv[8][4];
#pragma unroll
    for (int jt = 0; jt < 8; jt++) {
      float4 bb = *(const float4*)(b2 + jt * 16 + rowq * 4);
#pragma unroll
      for (int r = 0; r < 4; r++) {
        float v = acc[t][jt][r] + ((const float*)&bb)[r];
        vv[jt][r] = v; s1 += v; s2 += v * v;
      }
    }
    s1 += __shfl_xor(s1, 16, 64); s2 += __shfl_xor(s2, 16, 64);
    s1 += __shfl_xor(s1, 32, 64); s2 += __shfl_xor(s2, 32, 64);
    float mu = s1 * (1.f / 128.f);
    float rs = rsqrtf(s2 * (1.f / 128.f) - mu * mu + 1e-5f);
#pragma unroll
    for (int jt = 0; jt < 8; jt++) {
      float4 gg = *(const float4*)(g2 + jt * 16 + rowq * 4);
      float4 ee = *(const float4*)(be2 + jt * 16 + rowq * 4);
      ushort4 pk;
      unsigned short* pp = &pk.x;
#pragma unroll
      for (int r = 0; r < 4; r++) {
        float v = (vv[jt][r] - mu) * rs * ((const float*)&gg)[r] + ((const float*)&ee)[r];
        v = v / (1.f + __expf(-v));
        pp[r] = f2bu(v);
      }
      *(ushort4*)(sB + rbase[t] + (((unsigned)(jt * 32 + rowq * 8)) ^ swz[t])) = pk;
    }
  }

  // ---- layer 3: 128 -> 384 (jt-outer), LDS-staged coalesced output ----
  bf16x8 hf[4][4];
#pragma unroll
  for (int t = 0; t < 4; t++)
#pragma unroll
    for (int ks = 0; ks < 4; ks++)
      hf[t][ks] = *(const bf16x8*)(sB + rbase[t] + (((unsigned)(ks * 64 + rowq * 16)) ^ swz[t]));
  const int lq = lane & 15;
  const int eq = lane >> 4;
  for (int cc = 0; cc < 3; cc++) {
#pragma unroll
    for (int jj = 0; jj < 8; jj++) {
      int jt = cc * 8 + jj;
      bf16x8 wf[4];
#pragma unroll
      for (int ks = 0; ks < 4; ks++)
        wf[ks] = *(const bf16x8*)(W3T + (size_t)(jt * 16 + colq) * 128 + ks * 32 + rowq * 8);
      f32x4 a[4] = {zz, zz, zz, zz};
#pragma unroll
      for (int ks = 0; ks < 4; ks++)
#pragma unroll
        for (int t = 0; t < 4; t++)
          a[t] = __builtin_amdgcn_mfma_f32_16x16x32_bf16(wf[ks], hf[t][ks], a[t], 0, 0, 0);
      float4 bb = *(const float4*)(b3 + jt * 16 + rowq * 4);
#pragma unroll
      for (int t = 0; t < 4; t++) {
        ushort4 pk;
        unsigned short* pp = &pk.x;
#pragma unroll
        for (int r = 0; r < 4; r++) pp[r] = f2bu(a[t][r] + ((const float*)&bb)[r]);
        *(ushort4*)(sB + rbase[t] + (((unsigned)(jj * 32 + rowq * 8)) ^ swz[t])) = pk;
      }
    }
    // drain: 16 store instrs, each = 4 contiguous 256B segments (full lines)
#pragma unroll
    for (int i = 0; i < 16; i++) {
      int e2 = wid * 64 + i * 4 + eq;
      unsigned lo2 = ((unsigned)lq * 16) ^ ((unsigned)(e2 & 7) << 4);
      uint4 v = *(const uint4*)(sB + (unsigned)e2 * 256 + lo2);
      size_t gb = (size_t)(blockIdx.x * 128 + e2) * 768 + cc * 256 + lq * 16;
      *(uint4*)((char*)w_chunk + gb) = v;
    }
  }
}

// ---------------------------------------------------------------------------
// Kernel 2: per-edge rotate+conv+norm+logits, REGISTER-ONLY (bf16 mixes).
// ---------------------------------------------------------------------------
template <int STOREV>
__global__ __launch_bounds__(256) void edgeA_kernel(
    const unsigned short* __restrict__ qmixNb, const float* __restrict__ q0N,
    const unsigned short* __restrict__ kvmixNb, const float* __restrict__ kv0N,
    const float* __restrict__ Rw, const int* __restrict__ edge,
    const unsigned short* __restrict__ w_chunk, int e0,
    const float* __restrict__ qng, const float* __restrict__ kng,
    const float* __restrict__ kng0,
    __hip_bfloat16* __restrict__ v_buf, __hip_bfloat16* __restrict__ v0_buf,
    float* __restrict__ logits, unsigned* __restrict__ mx, int E) {
  const int g = threadIdx.x & 63;
  const int e = e0 + blockIdx.x * 4 + (threadIdx.x >> 6);
  const int src = edge[e], dst = edge[E + e];
  const int l = g & 1, cg = g >> 1;

  float R[5][5];
  {
    const float* rb = Rw + (size_t)e * 50 + l * 25;
#pragma unroll
    for (int m = 0; m < 5; m++)
#pragma unroll
      for (int n = 0; n < 5; n++) R[m][n] = rb[m * 5 + n];
  }
  float xr[5];
  {
    ushort8v xv = *(const ushort8v*)(kvmixNb + (size_t)src * 512 + g * 8);
    float x0 = bu2f(xv[0]), x1 = bu2f(xv[1]), x2 = bu2f(xv[2]),
          x3 = bu2f(xv[3]), x4 = bu2f(xv[4]);
#pragma unroll
    for (int m = 0; m < 5; m++)
      xr[m] = R[m][0] * x0 + R[m][1] * x1 + R[m][2] * x2 + R[m][3] * x3 + R[m][4] * x4;
  }
  const unsigned short* wa = w_chunk + (size_t)(e - e0) * 384;
  ushort4 wq = *(const ushort4*)(wa + 4 * g);
  float w0_ = bu2f(wq.x), w1_ = bu2f(wq.y), w2_ = bu2f(wq.z), w3_ = bu2f(wq.w);
  float wm = bu2f(wa[320 + g]);
  float y[5];
  y[0] = w3_ * xr[4] + w1_ * xr[0];
  y[1] = w2_ * xr[3] + w0_ * xr[1];
  y[2] = wm * xr[2];
  y[3] = w0_ * xr[3] - w2_ * xr[1];
  y[4] = w1_ * xr[4] - w3_ * xr[0];
  float y0 = bu2f(wa[256 + g]) * kv0N[(size_t)src * 64 + g];

  float p = 0.f;
  if (g < 32) p = y[0] * y[0] + y[1] * y[1] + y[2] * y[2] + y[3] * y[3] + y[4] * y[4];
  float rmsk = rsqrtf(waveSum(p) * (1.f / 160.f) + 1e-5f);
  float kngc = (g < 32) ? kng[cg] : 0.f;
  float yk[5];
#pragma unroll
  for (int m = 0; m < 5; m++) yk[m] = y[m] * rmsk * kngc;
  float k0v = (g < 32) ? y0 : 0.f;
  float s1 = waveSum(k0v), s2 = waveSum(k0v * k0v);
  float mu = s1 * (1.f / 32.f), var = s2 * (1.f / 32.f) - mu * mu;
  float k0n = (k0v - mu) * rsqrtf(var + 1e-5f) * ((g < 32) ? kng0[g] : 0.f);

  float qn[5];
  float q0 = 0.f;
  {
    float qx0 = 0.f, qx1 = 0.f, qx2 = 0.f, qx3 = 0.f, qx4 = 0.f;
    if (g < 32) {
      ushort8v qv = *(const ushort8v*)(qmixNb + (size_t)dst * 256 + g * 8);
      qx0 = bu2f(qv[0]); qx1 = bu2f(qv[1]); qx2 = bu2f(qv[2]);
      qx3 = bu2f(qv[3]); qx4 = bu2f(qv[4]);
      q0 = q0N[(size_t)dst * 32 + g];
    }
    float qr[5];
#pragma unroll
    for (int m = 0; m < 5; m++)
      qr[m] = R[m][0] * qx0 + R[m][1] * qx1 + R[m][2] * qx2 + R[m][3] * qx3 + R[m][4] * qx4;
    float pq = qr[0] * qr[0] + qr[1] * qr[1] + qr[2] * qr[2] + qr[3] * qr[3] + qr[4] * qr[4];
    float rmsq = rsqrtf(waveSum(pq) * (1.f / 160.f) + 1e-5f);
    float qngc = (g < 32) ? qng[cg] : 0.f;
#pragma unroll
    for (int m = 0; m < 5; m++) qn[m] = qr[m] * rmsq * qngc;
  }

  float part = qn[0] * yk[0] + qn[1] * yk[1] + qn[2] * yk[2] + qn[3] * yk[3] + qn[4] * yk[4]
             + q0 * k0n;
  part += __shfl_xor(part, 1, 64);
  part += __shfl_xor(part, 2, 64);
  if (g < 32 && (g & 3) == 0) {
    int h = g >> 2;
    float lg = part * 0.70710678118654752f;
    logits[(size_t)e * 8 + h] = lg;
    if (!STOREV) atomicMax(&mx[dst * 8 + h], encf(lg));
  }
  if (STOREV && g >= 32) {
    int j = g - 32;
    ushort8v pk;
    pk[0] = f2bu(y[0]); pk[1] = f2bu(y[1]); pk[2] = f2bu(y[2]);
    pk[3] = f2bu(y[3]); pk[4] = f2bu(y[4]); pk[5] = 0; pk[6] = 0; pk[7] = 0;
    *(ushort8v*)((char*)v_buf + ((size_t)e * 256 + j * 8) * 2) = pk;
    v0_buf[(size_t)e * 32 + j] = __float2bfloat16(y0);
  }
}

// ---------------------------------------------------------------------------
// Kernel 3 (fallback only): denominator
// ---------------------------------------------------------------------------
__global__ __launch_bounds__(256) void edge2_kernel(
    const int* __restrict__ edge, const float* __restrict__ logits,
    const unsigned* __restrict__ mx, float* __restrict__ den, int E) {
  int idx = blockIdx.x * 256 + threadIdx.x;
  if (idx >= E * 8) return;
  int e = idx >> 3, h = idx & 7;
  int dst = edge[E + e];
  float m = decf(mx[dst * 8 + h]);
  atomicAdd(&den[dst * 8 + h], __expf(logits[idx] - m));
}

// ---------------------------------------------------------------------------
// Kernel 4 (fast): per-NODE gather, parity-split, fused 2-pass softmax.
// ---------------------------------------------------------------------------
__global__ __launch_bounds__(256) void nodegather_kernel(
    const float* __restrict__ Rw, const int* __restrict__ csr,
    const int* __restrict__ rowstart,
    const __hip_bfloat16* __restrict__ v_buf, const __hip_bfloat16* __restrict__ v0_buf,
    const float* __restrict__ logits,
    float* __restrict__ att, float* __restrict__ att0, int N) {
  const int g = threadIdx.x & 63;
  const int n = blockIdx.x * 4 + (threadIdx.x >> 6);
  if (n >= N) return;
  const int row = rowstart[n];
  const int deg = rowstart[n + 1] - row;
  const int ep = g >> 5, gg = g & 31;
  const int l = gg & 1, h = gg >> 2;

  if (deg == 0) {
    if (g < 32) {
#pragma unroll
      for (int m = 0; m < 5; m++) att[(size_t)n * 160 + gg * 5 + m] = 0.f;
      att0[(size_t)n * 32 + gg] = 0.f;
    }
    return;
  }

  float mxh = -3.402823466e38f;
  for (int k = ep; k < deg; k += 2)
    mxh = fmaxf(mxh, logits[(size_t)csr[row + k] * 8 + h]);
  mxh = fmaxf(mxh, __shfl_xor(mxh, 32, 64));

  float acc[5] = {0.f, 0.f, 0.f, 0.f, 0.f};
  float acc0 = 0.f, den = 0.f;
  for (int k = ep; k < deg; k += 2) {
    int e = csr[row + k];
    float ex = __expf(logits[(size_t)e * 8 + h] - mxh);
    den += ex;
    uint4 vv = *(const uint4*)((const char*)v_buf + ((size_t)e * 256 + gg * 8) * 2);
    float v0_ = bu2f(vv.x & 0xffffu), v1_ = bu2f(vv.x >> 16);
    float v2_ = bu2f(vv.y & 0xffffu), v3_ = bu2f(vv.y >> 16);
    float v4_ = bu2f(vv.z & 0xffffu);
    const float* rb = Rw + (size_t)e * 50 + l * 25;
#pragma unroll
    for (int m = 0; m < 5; m++) {
      float o = rb[m] * v0_ + rb[5 + m] * v1_ + rb[10 + m] * v2_ +
                rb[15 + m] * v3_ + rb[20 + m] * v4_;
      acc[m] += ex * o;
    }
    acc0 += ex * __bfloat162float(v0_buf[(size_t)e * 32 + gg]);
  }
  den += __shfl_xor(den, 32, 64);
#pragma unroll
  for (int m = 0; m < 5; m++) acc[m] += __shfl_xor(acc[m], 32, 64);
  acc0 += __shfl_xor(acc0, 32, 64);
  float inv = 1.f / den;
  if (g < 32) {
#pragma unroll
    for (int m = 0; m < 5; m++) att[(size_t)n * 160 + gg * 5 + m] = acc[m] * inv;
    att0[(size_t)n * 32 + gg] = acc0 * inv;
  }
}

// ---------------------------------------------------------------------------
// Kernel 4b (fallback): recompute v branch, atomic scatter
// ---------------------------------------------------------------------------
__global__ __launch_bounds__(256) void edgeB_rec(
    const unsigned short* __restrict__ kvmixNb, const float* __restrict__ kv0N,
    const float* __restrict__ Rw, const int* __restrict__ edge,
    const unsigned short* __restrict__ w_chunk, int e0,
    const float* __restrict__ logits, const unsigned* __restrict__ mx,
    const float* __restrict__ den,
    float* __restrict__ att, float* __restrict__ att0, int E) {
  const int g = threadIdx.x & 63;
  const int e = e0 + blockIdx.x * 4 + (threadIdx.x >> 6);
  const int src = edge[e], dst = edge[E + e];
  const int l = g & 1;
  const int h = (g < 32) ? (g >> 2) : ((g - 32) >> 2);
  float m_ = decf(mx[dst * 8 + h]);
  float alpha = __expf(logits[(size_t)e * 8 + h] - m_) / den[dst * 8 + h];
  const unsigned short* wa = w_chunk + (size_t)(e - e0) * 384;
  if (g < 32) {
    const float* rb = Rw + (size_t)e * 50 + l * 25;
    float R[5][5];
#pragma unroll
    for (int a = 0; a < 5; a++)
#pragma unroll
      for (int b = 0; b < 5; b++) R[a][b] = rb[a * 5 + b];
    float xr[5];
    {
      ushort8v xv = *(const ushort8v*)(kvmixNb + (size_t)src * 512 + (32 + g) * 8);
      float x0 = bu2f(xv[0]), x1 = bu2f(xv[1]), x2 = bu2f(xv[2]),
            x3 = bu2f(xv[3]), x4 = bu2f(xv[4]);
#pragma unroll
      for (int m = 0; m < 5; m++)
        xr[m] = R[m][0] * x0 + R[m][1] * x1 + R[m][2] * x2 + R[m][3] * x3 + R[m][4] * x4;
    }
    ushort4 wq = *(const ushort4*)(wa + (32 + g) * 4);
    float w0_ = bu2f(wq.x), w1_ = bu2f(wq.y), w2_ = bu2f(wq.z), w3_ = bu2f(wq.w);
    float wm = bu2f(wa[352 + g]);
    float y[5];
    y[0] = w3_ * xr[4] + w1_ * xr[0];
    y[1] = w2_ * xr[3] + w0_ * xr[1];
    y[2] = wm * xr[2];
    y[3] = w0_ * xr[3] - w2_ * xr[1];
    y[4] = w1_ * xr[4] - w3_ * xr[0];
#pragma unroll
    for (int m = 0; m < 5; m++) {
      float o = R[0][m] * y[0] + R[1][m] * y[1] + R[2][m] * y[2] + R[3][m] * y[3] + R[4][m] * y[4];
      atomicAdd(&att[(size_t)dst * 160 + g * 5 + m], alpha * o);
    }
  } else {
    int j = g - 32;
    float v0 = bu2f(wa[288 + j]) * kv0N[(size_t)src * 64 + 32 + j];
    atomicAdd(&att0[(size_t)dst * 32 + j], alpha * v0);
  }
}

// ---------------------------------------------------------------------------
// Kernel 5: per-node output projection, in place over d_out
// ---------------------------------------------------------------------------
__global__ __launch_bounds__(256) void node_kernel(
    const float* __restrict__ pW, const float* __restrict__ pW0,
    const float* __restrict__ pb0, float* __restrict__ out, int N) {
  __shared__ float sA[4][160];
  __shared__ float sA0[4][32];
  const int tid = threadIdx.x;
  const int wv = tid >> 6, w = tid & 63;
  const int n = blockIdx.x * 4 + wv;
  if (n < N) {
    for (int i = w; i < 160; i += 64) sA[wv][i] = out[(size_t)n * 160 + i];
    if (w < 32) sA0[wv][w] = out[(size_t)N * 160 + (size_t)n * 32 + w];
  }
  __syncthreads();
  if (n >= N) return;
  for (int i = w; i < 160; i += 64) {
    int o = i / 10, lm = i % 10, l = lm / 5, m = lm % 5;
    float a = 0.f;
    const float* wr = pW + l * 256 + o * 16;
#pragma unroll
    for (int c = 0; c < 16; c++) a += wr[c] * sA[wv][c * 10 + l * 5 + m];
    out[(size_t)n * 160 + i] = a;
  }
  if (w < 32) {
    float a = pb0[w];
    const float* wr = pW0 + w * 32;
#pragma unroll
    for (int c = 0; c < 32; c++) a += wr[c] * sA0[wv][c];
    out[(size_t)N * 160 + (size_t)n * 32 + w] = a;
  }
}

// ---------------------------------------------------------------------------
extern "C" void kernel_launch(void* const* d_in, const int* in_sizes, int n_in,
                              void* d_out, int out_size, void* d_ws, size_t ws_size,
                              hipStream_t stream) {
  const float* x_src  = (const float*)d_in[0];
  const float* x_tar  = (const float*)d_in[1];
  const float* x_src0 = (const float*)d_in[2];
  const float* x_tar0 = (const float*)d_in[3];
  const float* Rw     = (const float*)d_in[4];
  const float* ef     = (const float*)d_in[5];
  const int*   edge   = (const int*)d_in[6];
  const float* r_W1 = (const float*)d_in[10];
  const float* r_b1 = (const float*)d_in[11];
  const float* r_g1 = (const float*)d_in[12];
  const float* r_be1 = (const float*)d_in[13];
  const float* r_W2 = (const float*)d_in[14];
  const float* r_b2 = (const float*)d_in[15];
  const float* r_g2 = (const float*)d_in[16];
  const float* r_be2 = (const float*)d_in[17];
  const float* r_W3 = (const float*)d_in[18];
  const float* r_b3 = (const float*)d_in[19];
  const float* qW  = (const float*)d_in[20];
  const float* qW0 = (const float*)d_in[21];
  const float* qb0 = (const float*)d_in[22];
  const float* kvW  = (const float*)d_in[23];
  const float* kvW0 = (const float*)d_in[24];
  const float* kvb0 = (const float*)d_in[25];
  const float* qng  = (const float*)d_in[26];
  const float* qng0 = (const float*)d_in[27];
  const float* kng  = (const float*)d_in[28];
  const float* kng0 = (const float*)d_in[29];
  const float* pW  = (const float*)d_in[30];
  const float* pW0 = (const float*)d_in[31];
  const float* pb0 = (const float*)d_in[32];

  const int N = in_sizes[0] / 160;   // 10000
  const int E = in_sizes[4] / 50;    // 160000
  float* out = (float*)d_out;

  char* ws = (char*)d_ws;
  size_t off = 0;
  auto alloc = [&](size_t bytes) {
    void* p = ws + off;
    off += (bytes + 255) & ~(size_t)255;
    return p;
  };
  unsigned short* W1T = (unsigned short*)alloc(128 * 32 * 2);
  unsigned short* W2T = (unsigned short*)alloc(128 * 128 * 2);
  unsigned short* W3T = (unsigned short*)alloc(384 * 128 * 2);
  float* logits = (float*)alloc((size_t)E * 8 * 4);
  int* rowstart = (int*)alloc((size_t)(N + 1) * 4);
  int* csr      = (int*)alloc((size_t)E * 4);
  size_t zoff = off;
  int* cnt    = (int*)alloc((size_t)N * 4);
  int* cursor = (int*)alloc((size_t)N * 4);
  unsigned* mxb = (unsigned*)alloc((size_t)N * 8 * 4);
  float* den = (float*)alloc((size_t)N * 8 * 4);
  size_t zend = off;
  unsigned short* qmixNb  = (unsigned short*)alloc((size_t)N * 256 * 2);
  float* q0N    = (float*)alloc((size_t)N * 32 * 4);
  unsigned short* kvmixNb = (unsigned short*)alloc((size_t)N * 512 * 2);
  float* kv0N   = (float*)alloc((size_t)N * 64 * 4);

  // per-edge chunk bytes: w_chunk (768) only — h1/h2 live in LDS
  if (ws_size <= off + 128 * 768) return;
  size_t avail = ws_size - off;
  const size_t vsz = (size_t)E * 256 * 2 + (size_t)E * 32 * 2 + 512;
  bool fast = false;
  size_t CE;
  __hip_bfloat16 *vb = nullptr, *v0b = nullptr;
  if (avail >= vsz + (size_t)1024 * 768) {
    fast = true;
    vb  = (__hip_bfloat16*)alloc((size_t)E * 256 * 2);
    v0b = (__hip_bfloat16*)alloc((size_t)E * 32 * 2);
    CE = (ws_size - off) / 768;
  } else {
    CE = avail / 768;
  }
  if (CE > (size_t)E) CE = E;
  CE &= ~(size_t)127;
  if (CE == 0) return;
  unsigned short* w_chunk = (unsigned short*)(ws + off);

  hipMemsetAsync(ws + zoff, 0, zend - zoff, stream);
  hipMemsetAsync(d_out, 0, (size_t)out_size * 4, stream);

  prep_kernel<<<(69632 + 255) / 256, 256, 0, stream>>>(r_W1, r_W2, r_W3, W1T, W2T, W3T);
  nodeprep_kernel<<<(N + 3) / 4, 256, 0, stream>>>(
      x_tar, x_tar0, x_src, x_src0, qW, qW0, qb0, qng0, kvW, kvW0, kvb0,
      qmixNb, q0N, kvmixNb, kv0N, N);
  count_kernel<<<(E + 255) / 256, 256, 0, stream>>>(edge, cnt, E);
  scan_kernel<<<1, 1024, 0, stream>>>(cnt, rowstart, N);
  fill_kernel<<<(E + 255) / 256, 256, 0, stream>>>(edge, rowstart, cursor, csr, E);

  for (int e0 = 0; e0 < E; e0 += (int)CE) {
    int cnt_ = E - e0 < (int)CE ? E - e0 : (int)CE;
    radial_fused<<<(cnt_ + 127) / 128, 128, 0, stream>>>(
        ef, W1T, W2T, W3T, r_b1, r_g1, r_be1, r_b2, r_g2, r_be2, r_b3, w_chunk, e0);
    if (fast)
      edgeA_kernel<1><<<cnt_ / 4, 256, 0, stream>>>(qmixNb, q0N, kvmixNb, kv0N, Rw, edge,
                                                    w_chunk, e0, qng, kng, kng0,
                                                    vb, v0b, logits, mxb, E);
    else
      edgeA_kernel<0><<<cnt_ / 4, 256, 0, stream>>>(qmixNb, q0N, kvmixNb, kv0N, Rw, edge,
                                                    w_chunk, e0, qng, kng, kng0,
                                                    vb, v0b, logits, mxb, E);
  }
  float* att  = out;
  float* att0 = out + (size_t)N * 160;
  if (fast) {
    nodegather_kernel<<<(N + 3) / 4, 256, 0, stream>>>(Rw, csr, rowstart, vb, v0b,
                                                       logits, att, att0, N);
  } else {
    edge2_kernel<<<(E * 8 + 255) / 256, 256, 0, stream>>>(edge, logits, mxb, den, E);
    for (int e0 = 0; e0 < E; e0 += (int)CE) {
      int cnt_ = E - e0 < (int)CE ? E - e0 : (int)CE;
      radial_fused<<<(cnt_ + 127) / 128, 128, 0, stream>>>(
          ef, W1T, W2T, W3T, r_b1, r_g1, r_be1, r_b2, r_g2, r_be2, r_b3, w_chunk, e0);
      edgeB_rec<<<cnt_ / 4, 256, 0, stream>>>(kvmixNb, kv0N, Rw, edge, w_chunk, e0,
                                              logits, mxb, den, att, att0, E);
    }
  }
  node_kernel<<<(N + 3) / 4, 256, 0, stream>>>(pW, pW0, pb0, out, N);
}

// Round 15
// 338.279 us; speedup vs baseline: 1.1791x; 1.1791x over previous
//
#include <hip/hip_runtime.h>
#include <hip/hip_bf16.h>
#include <math.h>

// N=10000, E=160000, C=16, C0=32, L=2, M=5, H=8, R_IN=32, R_HID=128, REQ=384

typedef short bf16x8 __attribute__((ext_vector_type(8)));
typedef float f32x4 __attribute__((ext_vector_type(4)));
typedef unsigned short ushort8v __attribute__((ext_vector_type(8)));

__device__ __forceinline__ float waveSum(float v) {
#pragma unroll
  for (int m = 1; m < 64; m <<= 1) v += __shfl_xor(v, m, 64);
  return v;
}
__device__ __forceinline__ unsigned encf(float f) {
  unsigned u = __float_as_uint(f);
  return (u & 0x80000000u) ? ~u : (u | 0x80000000u);
}
__device__ __forceinline__ float decf(unsigned u) {
  return (u & 0x80000000u) ? __uint_as_float(u & 0x7FFFFFFFu) : __uint_as_float(~u);
}
__device__ __forceinline__ unsigned short f2bu(float f) {
  __hip_bfloat16 h = __float2bfloat16(f);
  unsigned short u;
  __builtin_memcpy(&u, &h, 2);
  return u;
}
__device__ __forceinline__ float bu2f(unsigned u16) {
  unsigned x = u16 << 16;
  float f;
  __builtin_memcpy(&f, &x, 4);
  return f;
}

// ---------------------------------------------------------------------------
// Prep: transpose radial weights to bf16 [n][k] layout
// ---------------------------------------------------------------------------
__global__ __launch_bounds__(256) void prep_kernel(
    const float* __restrict__ W1, const float* __restrict__ W2,
    const float* __restrict__ W3,
    unsigned short* __restrict__ W1T, unsigned short* __restrict__ W2T,
    unsigned short* __restrict__ W3T) {
  int idx = blockIdx.x * 256 + threadIdx.x;
  if (idx < 128 * 32) {
    int n = idx >> 5, k = idx & 31;
    W1T[idx] = f2bu(W1[k * 128 + n]);
  }
  int i2 = idx - 128 * 32;
  if (i2 >= 0 && i2 < 128 * 128) {
    int n = i2 >> 7, k = i2 & 127;
    W2T[i2] = f2bu(W2[k * 128 + n]);
  }
  int i3 = idx - 128 * 32 - 128 * 128;
  if (i3 >= 0 && i3 < 384 * 128) {
    int n = i3 >> 7, k = i3 & 127;
    W3T[i3] = f2bu(W3[k * 384 + n]);
  }
}

// ---------------------------------------------------------------------------
// CSR build: count, scan (1 block), fill
// ---------------------------------------------------------------------------
__global__ __launch_bounds__(256) void count_kernel(const int* __restrict__ edge,
                                                    int* __restrict__ cnt, int E) {
  int e = blockIdx.x * 256 + threadIdx.x;
  if (e < E) atomicAdd(&cnt[edge[E + e]], 1);
}

__global__ __launch_bounds__(1024) void scan_kernel(const int* __restrict__ cnt,
                                                    int* __restrict__ rowstart, int N) {
  __shared__ int sp[1024];
  const int t = threadIdx.x;
  const int chunk = (N + 1023) >> 10;
  const int beg = t * chunk;
  const int end = min(beg + chunk, N);
  int s = 0;
  for (int i = beg; i < end; i++) s += cnt[i];
  sp[t] = s;
  __syncthreads();
  for (int off = 1; off < 1024; off <<= 1) {
    int tmp = (t >= off) ? sp[t - off] : 0;
    __syncthreads();
    sp[t] += tmp;
    __syncthreads();
  }
  int excl = sp[t] - s;
  int run = excl;
  for (int i = beg; i < end; i++) { rowstart[i] = run; run += cnt[i]; }
  if (t == 0) rowstart[N] = sp[1023];
}

__global__ __launch_bounds__(256) void fill_kernel(const int* __restrict__ edge,
                                                   const int* __restrict__ rowstart,
                                                   int* __restrict__ cursor,
                                                   int* __restrict__ csr, int E) {
  int e = blockIdx.x * 256 + threadIdx.x;
  if (e < E) {
    int d = edge[E + e];
    int p = atomicAdd(&cursor[d], 1);
    csr[rowstart[d] + p] = e;
  }
}

// ---------------------------------------------------------------------------
// Node prep: hoist channel-mix GEMMs to nodes.  Mixes stored bf16 padded
// [node][group][8] so edgeA's per-lane gather is one aligned 16B load.
// ---------------------------------------------------------------------------
__global__ __launch_bounds__(256) void nodeprep_kernel(
    const float* __restrict__ xt, const float* __restrict__ xt0,
    const float* __restrict__ xs, const float* __restrict__ xs0,
    const float* __restrict__ qW, const float* __restrict__ qW0,
    const float* __restrict__ qb0, const float* __restrict__ qng0,
    const float* __restrict__ kvW, const float* __restrict__ kvW0,
    const float* __restrict__ kvb0,
    unsigned short* __restrict__ qmixNb, float* __restrict__ q0N,
    unsigned short* __restrict__ kvmixNb, float* __restrict__ kv0N, int N) {
  __shared__ float sXT[4][160];
  __shared__ float sXS[4][160];
  __shared__ float sX0T[4][32];
  __shared__ float sX0S[4][32];
  const int tid = threadIdx.x, wv = tid >> 6, w = tid & 63;
  const int n = blockIdx.x * 4 + wv;
  if (n < N) {
    for (int i = w; i < 160; i += 64) {
      sXT[wv][i] = xt[(size_t)n * 160 + i];
      sXS[wv][i] = xs[(size_t)n * 160 + i];
    }
    if (w < 32) { sX0T[wv][w] = xt0[n * 32 + w]; sX0S[wv][w] = xs0[n * 32 + w]; }
  }
  __syncthreads();
  if (n >= N) return;
  for (int i = w; i < 160; i += 64) {
    int o = i / 10, lm = i % 10, l = lm / 5, m = lm % 5;
    const float4* wr = (const float4*)(qW + l * 256 + o * 16);
    float a = 0.f;
#pragma unroll
    for (int c4 = 0; c4 < 4; c4++) {
      float4 ww = wr[c4];
      a += ww.x * sXT[wv][(c4 * 4 + 0) * 10 + lm] + ww.y * sXT[wv][(c4 * 4 + 1) * 10 + lm]
         + ww.z * sXT[wv][(c4 * 4 + 2) * 10 + lm] + ww.w * sXT[wv][(c4 * 4 + 3) * 10 + lm];
    }
    qmixNb[(size_t)n * 256 + (o * 2 + l) * 8 + m] = f2bu(a);
  }
  for (int i = w; i < 320; i += 64) {
    int o = i / 10, lm = i % 10, l = lm / 5, m = lm % 5;
    const float4* wr = (const float4*)(kvW + l * 512 + o * 16);
    float a = 0.f;
#pragma unroll
    for (int c4 = 0; c4 < 4; c4++) {
      float4 ww = wr[c4];
      a += ww.x * sXS[wv][(c4 * 4 + 0) * 10 + lm] + ww.y * sXS[wv][(c4 * 4 + 1) * 10 + lm]
         + ww.z * sXS[wv][(c4 * 4 + 2) * 10 + lm] + ww.w * sXS[wv][(c4 * 4 + 3) * 10 + lm];
    }
    kvmixNb[(size_t)n * 512 + (o * 2 + l) * 8 + m] = f2bu(a);
  }
  {
    float a = 0.f;
    if (w < 32) {
      a = qb0[w];
      const float4* wr = (const float4*)(qW0 + w * 32);
#pragma unroll
      for (int c4 = 0; c4 < 8; c4++) {
        float4 ww = wr[c4];
        a += ww.x * sX0T[wv][c4 * 4] + ww.y * sX0T[wv][c4 * 4 + 1]
           + ww.z * sX0T[wv][c4 * 4 + 2] + ww.w * sX0T[wv][c4 * 4 + 3];
      }
    }
    float vv = (w < 32) ? a : 0.f;
    float s1 = waveSum(vv), s2 = waveSum(vv * vv);
    float mu = s1 / 32.f, var = s2 / 32.f - mu * mu;
    if (w < 32) q0N[(size_t)n * 32 + w] = (a - mu) * rsqrtf(var + 1e-5f) * qng0[w];
  }
  {
    float a = kvb0[w];
    const float4* wr = (const float4*)(kvW0 + w * 32);
#pragma unroll
    for (int c4 = 0; c4 < 8; c4++) {
      float4 ww = wr[c4];
      a += ww.x * sX0S[wv][c4 * 4] + ww.y * sX0S[wv][c4 * 4 + 1]
         + ww.z * sX0S[wv][c4 * 4 + 2] + ww.w * sX0S[wv][c4 * 4 + 3];
    }
    kv0N[(size_t)n * 64 + w] = a;
  }
}

// ---------------------------------------------------------------------------
// Fused radial MLP (r13-verified config): zero barriers, 64 edges/WAVE,
// 256 edges/block, launch_bounds(256,2) -> 128 VGPR, NO spill (r14's
// (128,3) allocated 84 VGPR and spilled acc[4][8]: WRITE +103MB, 1.8x dur).
// LDS 64KB wave-private; L1/L2 ks-outer, L3 jt-outer; LDS-staged stores.
// ---------------------------------------------------------------------------
__global__ __launch_bounds__(256, 2) void radial_fused(
    const float* __restrict__ ef,
    const unsigned short* __restrict__ W1T, const unsigned short* __restrict__ W2T,
    const unsigned short* __restrict__ W3T,
    const float* __restrict__ b1, const float* __restrict__ g1, const float* __restrict__ be1,
    const float* __restrict__ b2, const float* __restrict__ g2, const float* __restrict__ be2,
    const float* __restrict__ b3,
    unsigned short* __restrict__ w_chunk, int e0) {
  __shared__ unsigned short sH[256 * 128];  // 64KB
  const int lane = threadIdx.x & 63;
  const int wid = threadIdx.x >> 6;
  const int colq = lane & 15, rowq = lane >> 4;
  int el[4], eg[4];
  unsigned swz[4], rbase[4];
#pragma unroll
  for (int t = 0; t < 4; t++) {
    el[t] = wid * 64 + t * 16 + colq;
    eg[t] = blockIdx.x * 256 + el[t];
    swz[t] = (unsigned)(el[t] & 7) << 4;
    rbase[t] = (unsigned)el[t] * 256;
  }
  char* sB = (char*)sH;
  f32x4 zz = {0.f, 0.f, 0.f, 0.f};

  // ---- layer 1: 32 -> 128 ----
  bf16x8 bfr[4];
#pragma unroll
  for (int t = 0; t < 4; t++) {
    const float* p = ef + (size_t)(e0 + eg[t]) * 32 + rowq * 8;
    float4 a = *(const float4*)p, b = *(const float4*)(p + 4);
    bfr[t][0] = (short)f2bu(a.x); bfr[t][1] = (short)f2bu(a.y);
    bfr[t][2] = (short)f2bu(a.z); bfr[t][3] = (short)f2bu(a.w);
    bfr[t][4] = (short)f2bu(b.x); bfr[t][5] = (short)f2bu(b.y);
    bfr[t][6] = (short)f2bu(b.z); bfr[t][7] = (short)f2bu(b.w);
  }
  f32x4 acc[4][8];
#pragma unroll
  for (int jt = 0; jt < 8; jt++) {
    bf16x8 wl = *(const bf16x8*)(W1T + (jt * 16 + colq) * 32 + rowq * 8);
#pragma unroll
    for (int t = 0; t < 4; t++)
      acc[t][jt] = __builtin_amdgcn_mfma_f32_16x16x32_bf16(wl, bfr[t], zz, 0, 0, 0);
  }
#pragma unroll
  for (int t = 0; t < 4; t++) {
    float s1 = 0.f, s2 = 0.f;
    float vv[8][4];
#pragma unroll
    for (int jt = 0; jt < 8; jt++) {
      float4 bb = *(const float4*)(b1 + jt * 16 + rowq * 4);
#pragma unroll
      for (int r = 0; r < 4; r++) {
        float v = acc[t][jt][r] + ((const float*)&bb)[r];
        vv[jt][r] = v; s1 += v; s2 += v * v;
      }
    }
    s1 += __shfl_xor(s1, 16, 64); s2 += __shfl_xor(s2, 16, 64);
    s1 += __shfl_xor(s1, 32, 64); s2 += __shfl_xor(s2, 32, 64);
    float mu = s1 * (1.f / 128.f);
    float rs = rsqrtf(s2 * (1.f / 128.f) - mu * mu + 1e-5f);
#pragma unroll
    for (int jt = 0; jt < 8; jt++) {
      float4 gg = *(const float4*)(g1 + jt * 16 + rowq * 4);
      float4 ee = *(const float4*)(be1 + jt * 16 + rowq * 4);
      ushort4 pk;
      unsigned short* pp = &pk.x;
#pragma unroll
      for (int r = 0; r < 4; r++) {
        float v = (vv[jt][r] - mu) * rs * ((const float*)&gg)[r] + ((const float*)&ee)[r];
        v = v / (1.f + __expf(-v));
        pp[r] = f2bu(v);
      }
      *(ushort4*)(sB + rbase[t] + (((unsigned)(jt * 32 + rowq * 8)) ^ swz[t])) = pk;
    }
  }

  // ---- layer 2: 128 -> 128 (ks-outer: one weight fragment feeds 4 MFMAs) ----
#pragma unroll
  for (int t = 0; t < 4; t++)
#pragma unroll
    for (int jt = 0; jt < 8; jt++) acc[t][jt] = zz;
#pragma unroll
  for (int ks = 0; ks < 4; ks++) {
    bf16x8 hh[4];
#pragma unroll
    for (int t = 0; t < 4; t++)
      hh[t] = *(const bf16x8*)(sB + rbase[t] + (((unsigned)(ks * 64 + rowq * 16)) ^ swz[t]));
#pragma unroll
    for (int jt = 0; jt < 8; jt++) {
      bf16x8 wf = *(const bf16x8*)(W2T + (size_t)(jt * 16 + colq) * 128 + ks * 32 + rowq * 8);
#pragma unroll
      for (int t = 0; t < 4; t++)
        acc[t][jt] = __builtin_amdgcn_mfma_f32_16x16x32_bf16(wf, hh[t], acc[t][jt], 0, 0, 0);
    }
  }
#pragma unroll
  for (int t = 0; t < 4; t++) {
    float s1 = 0.f, s2 = 0.f;
    float vv[8][4];
#pragma unroll
    for (int jt = 0; jt < 8; jt++) {
      float4 bb = *(const float4*)(b2 + jt * 16 + rowq * 4);
#pragma unroll
      for (int r = 0; r < 4; r++) {
        float v = acc[t][jt][r] + ((const float*)&bb)[r];
        vv[jt][r] = v; s1 += v; s2 += v * v;
      }
    }
    s1 += __shfl_xor(s1, 16, 64); s2 += __shfl_xor(s2, 16, 64);
    s1 += __shfl_xor(s1, 32, 64); s2 += __shfl_xor(s2, 32, 64);
    float mu = s1 * (1.f / 128.f);
    float rs = rsqrtf(s2 * (1.f / 128.f) - mu * mu + 1e-5f);
#pragma unroll
    for (int jt = 0; jt < 8; jt++) {
      float4 gg = *(const float4*)(g2 + jt * 16 + rowq * 4);
      float4 ee = *(const float4*)(be2 + jt * 16 + rowq * 4);
      ushort4 pk;
      unsigned short* pp = &pk.x;
#pragma unroll
      for (int r = 0; r < 4; r++) {
        float v = (vv[jt][r] - mu) * rs * ((const float*)&gg)[r] + ((const float*)&ee)[r];
        v = v / (1.f + __expf(-v));
        pp[r] = f2bu(v);
      }
      *(ushort4*)(sB + rbase[t] + (((unsigned)(jt * 32 + rowq * 8)) ^ swz[t])) = pk;
    }
  }

  // ---- layer 3: 128 -> 384 (jt-outer), LDS-staged coalesced output ----
  bf16x8 hf[4][4];
#pragma unroll
  for (int t = 0; t < 4; t++)
#pragma unroll
    for (int ks = 0; ks < 4; ks++)
      hf[t][ks] = *(const bf16x8*)(sB + rbase[t] + (((unsigned)(ks * 64 + rowq * 16)) ^ swz[t]));
  const int lq = lane & 15;
  const int eq = lane >> 4;
  for (int cc = 0; cc < 3; cc++) {
#pragma unroll
    for (int jj = 0; jj < 8; jj++) {
      int jt = cc * 8 + jj;
      bf16x8 wf[4];
#pragma unroll
      for (int ks = 0; ks < 4; ks++)
        wf[ks] = *(const bf16x8*)(W3T + (size_t)(jt * 16 + colq) * 128 + ks * 32 + rowq * 8);
      f32x4 a[4] = {zz, zz, zz, zz};
#pragma unroll
      for (int ks = 0; ks < 4; ks++)
#pragma unroll
        for (int t = 0; t < 4; t++)
          a[t] = __builtin_amdgcn_mfma_f32_16x16x32_bf16(wf[ks], hf[t][ks], a[t], 0, 0, 0);
      float4 bb = *(const float4*)(b3 + jt * 16 + rowq * 4);
#pragma unroll
      for (int t = 0; t < 4; t++) {
        ushort4 pk;
        unsigned short* pp = &pk.x;
#pragma unroll
        for (int r = 0; r < 4; r++) pp[r] = f2bu(a[t][r] + ((const float*)&bb)[r]);
        *(ushort4*)(sB + rbase[t] + (((unsigned)(jj * 32 + rowq * 8)) ^ swz[t])) = pk;
      }
    }
    // drain: 16 store instrs, each = 4 contiguous 256B segments (full lines)
#pragma unroll
    for (int i = 0; i < 16; i++) {
      int e2 = wid * 64 + i * 4 + eq;
      unsigned lo2 = ((unsigned)lq * 16) ^ ((unsigned)(e2 & 7) << 4);
      uint4 v = *(const uint4*)(sB + (unsigned)e2 * 256 + lo2);
      size_t gb = (size_t)(blockIdx.x * 256 + e2) * 768 + cc * 256 + lq * 16;
      *(uint4*)((char*)w_chunk + gb) = v;
    }
  }
}

// ---------------------------------------------------------------------------
// Kernel 2: per-edge rotate+conv+norm+logits, REGISTER-ONLY (bf16 mixes).
// ---------------------------------------------------------------------------
template <int STOREV>
__global__ __launch_bounds__(256) void edgeA_kernel(
    const unsigned short* __restrict__ qmixNb, const float* __restrict__ q0N,
    const unsigned short* __restrict__ kvmixNb, const float* __restrict__ kv0N,
    const float* __restrict__ Rw, const int* __restrict__ edge,
    const unsigned short* __restrict__ w_chunk, int e0,
    const float* __restrict__ qng, const float* __restrict__ kng,
    const float* __restrict__ kng0,
    __hip_bfloat16* __restrict__ v_buf, __hip_bfloat16* __restrict__ v0_buf,
    float* __restrict__ logits, unsigned* __restrict__ mx, int E) {
  const int g = threadIdx.x & 63;
  const int e = e0 + blockIdx.x * 4 + (threadIdx.x >> 6);
  const int src = edge[e], dst = edge[E + e];
  const int l = g & 1, cg = g >> 1;

  float R[5][5];
  {
    const float* rb = Rw + (size_t)e * 50 + l * 25;
#pragma unroll
    for (int m = 0; m < 5; m++)
#pragma unroll
      for (int n = 0; n < 5; n++) R[m][n] = rb[m * 5 + n];
  }
  float xr[5];
  {
    ushort8v xv = *(const ushort8v*)(kvmixNb + (size_t)src * 512 + g * 8);
    float x0 = bu2f(xv[0]), x1 = bu2f(xv[1]), x2 = bu2f(xv[2]),
          x3 = bu2f(xv[3]), x4 = bu2f(xv[4]);
#pragma unroll
    for (int m = 0; m < 5; m++)
      xr[m] = R[m][0] * x0 + R[m][1] * x1 + R[m][2] * x2 + R[m][3] * x3 + R[m][4] * x4;
  }
  const unsigned short* wa = w_chunk + (size_t)(e - e0) * 384;
  ushort4 wq = *(const ushort4*)(wa + 4 * g);
  float w0_ = bu2f(wq.x), w1_ = bu2f(wq.y), w2_ = bu2f(wq.z), w3_ = bu2f(wq.w);
  float wm = bu2f(wa[320 + g]);
  float y[5];
  y[0] = w3_ * xr[4] + w1_ * xr[0];
  y[1] = w2_ * xr[3] + w0_ * xr[1];
  y[2] = wm * xr[2];
  y[3] = w0_ * xr[3] - w2_ * xr[1];
  y[4] = w1_ * xr[4] - w3_ * xr[0];
  float y0 = bu2f(wa[256 + g]) * kv0N[(size_t)src * 64 + g];

  float p = 0.f;
  if (g < 32) p = y[0] * y[0] + y[1] * y[1] + y[2] * y[2] + y[3] * y[3] + y[4] * y[4];
  float rmsk = rsqrtf(waveSum(p) * (1.f / 160.f) + 1e-5f);
  float kngc = (g < 32) ? kng[cg] : 0.f;
  float yk[5];
#pragma unroll
  for (int m = 0; m < 5; m++) yk[m] = y[m] * rmsk * kngc;
  float k0v = (g < 32) ? y0 : 0.f;
  float s1 = waveSum(k0v), s2 = waveSum(k0v * k0v);
  float mu = s1 * (1.f / 32.f), var = s2 * (1.f / 32.f) - mu * mu;
  float k0n = (k0v - mu) * rsqrtf(var + 1e-5f) * ((g < 32) ? kng0[g] : 0.f);

  float qn[5];
  float q0 = 0.f;
  {
    float qx0 = 0.f, qx1 = 0.f, qx2 = 0.f, qx3 = 0.f, qx4 = 0.f;
    if (g < 32) {
      ushort8v qv = *(const ushort8v*)(qmixNb + (size_t)dst * 256 + g * 8);
      qx0 = bu2f(qv[0]); qx1 = bu2f(qv[1]); qx2 = bu2f(qv[2]);
      qx3 = bu2f(qv[3]); qx4 = bu2f(qv[4]);
      q0 = q0N[(size_t)dst * 32 + g];
    }
    float qr[5];
#pragma unroll
    for (int m = 0; m < 5; m++)
      qr[m] = R[m][0] * qx0 + R[m][1] * qx1 + R[m][2] * qx2 + R[m][3] * qx3 + R[m][4] * qx4;
    float pq = qr[0] * qr[0] + qr[1] * qr[1] + qr[2] * qr[2] + qr[3] * qr[3] + qr[4] * qr[4];
    float rmsq = rsqrtf(waveSum(pq) * (1.f / 160.f) + 1e-5f);
    float qngc = (g < 32) ? qng[cg] : 0.f;
#pragma unroll
    for (int m = 0; m < 5; m++) qn[m] = qr[m] * rmsq * qngc;
  }

  float part = qn[0] * yk[0] + qn[1] * yk[1] + qn[2] * yk[2] + qn[3] * yk[3] + qn[4] * yk[4]
             + q0 * k0n;
  part += __shfl_xor(part, 1, 64);
  part += __shfl_xor(part, 2, 64);
  if (g < 32 && (g & 3) == 0) {
    int h = g >> 2;
    float lg = part * 0.70710678118654752f;
    logits[(size_t)e * 8 + h] = lg;
    if (!STOREV) atomicMax(&mx[dst * 8 + h], encf(lg));
  }
  if (STOREV && g >= 32) {
    int j = g - 32;
    ushort8v pk;
    pk[0] = f2bu(y[0]); pk[1] = f2bu(y[1]); pk[2] = f2bu(y[2]);
    pk[3] = f2bu(y[3]); pk[4] = f2bu(y[4]); pk[5] = 0; pk[6] = 0; pk[7] = 0;
    *(ushort8v*)((char*)v_buf + ((size_t)e * 256 + j * 8) * 2) = pk;
    v0_buf[(size_t)e * 32 + j] = __float2bfloat16(y0);
  }
}

// ---------------------------------------------------------------------------
// Kernel 3 (fallback only): denominator
// ---------------------------------------------------------------------------
__global__ __launch_bounds__(256) void edge2_kernel(
    const int* __restrict__ edge, const float* __restrict__ logits,
    const unsigned* __restrict__ mx, float* __restrict__ den, int E) {
  int idx = blockIdx.x * 256 + threadIdx.x;
  if (idx >= E * 8) return;
  int e = idx >> 3, h = idx & 7;
  int dst = edge[E + e];
  float m = decf(mx[dst * 8 + h]);
  atomicAdd(&den[dst * 8 + h], __expf(logits[idx] - m));
}

// ---------------------------------------------------------------------------
// Kernel 4 (fast): per-NODE gather, parity-split, fused 2-pass softmax.
// ---------------------------------------------------------------------------
__global__ __launch_bounds__(256) void nodegather_kernel(
    const float* __restrict__ Rw, const int* __restrict__ csr,
    const int* __restrict__ rowstart,
    const __hip_bfloat16* __restrict__ v_buf, const __hip_bfloat16* __restrict__ v0_buf,
    const float* __restrict__ logits,
    float* __restrict__ att, float* __restrict__ att0, int N) {
  const int g = threadIdx.x & 63;
  const int n = blockIdx.x * 4 + (threadIdx.x >> 6);
  if (n >= N) return;
  const int row = rowstart[n];
  const int deg = rowstart[n + 1] - row;
  const int ep = g >> 5, gg = g & 31;
  const int l = gg & 1, h = gg >> 2;

  if (deg == 0) {
    if (g < 32) {
#pragma unroll
      for (int m = 0; m < 5; m++) att[(size_t)n * 160 + gg * 5 + m] = 0.f;
      att0[(size_t)n * 32 + gg] = 0.f;
    }
    return;
  }

  float mxh = -3.402823466e38f;
  for (int k = ep; k < deg; k += 2)
    mxh = fmaxf(mxh, logits[(size_t)csr[row + k] * 8 + h]);
  mxh = fmaxf(mxh, __shfl_xor(mxh, 32, 64));

  float acc[5] = {0.f, 0.f, 0.f, 0.f, 0.f};
  float acc0 = 0.f, den = 0.f;
  for (int k = ep; k < deg; k += 2) {
    int e = csr[row + k];
    float ex = __expf(logits[(size_t)e * 8 + h] - mxh);
    den += ex;
    uint4 vv = *(const uint4*)((const char*)v_buf + ((size_t)e * 256 + gg * 8) * 2);
    float v0_ = bu2f(vv.x & 0xffffu), v1_ = bu2f(vv.x >> 16);
    float v2_ = bu2f(vv.y & 0xffffu), v3_ = bu2f(vv.y >> 16);
    float v4_ = bu2f(vv.z & 0xffffu);
    const float* rb = Rw + (size_t)e * 50 + l * 25;
#pragma unroll
    for (int m = 0; m < 5; m++) {
      float o = rb[m] * v0_ + rb[5 + m] * v1_ + rb[10 + m] * v2_ +
                rb[15 + m] * v3_ + rb[20 + m] * v4_;
      acc[m] += ex * o;
    }
    acc0 += ex * __bfloat162float(v0_buf[(size_t)e * 32 + gg]);
  }
  den += __shfl_xor(den, 32, 64);
#pragma unroll
  for (int m = 0; m < 5; m++) acc[m] += __shfl_xor(acc[m], 32, 64);
  acc0 += __shfl_xor(acc0, 32, 64);
  float inv = 1.f / den;
  if (g < 32) {
#pragma unroll
    for (int m = 0; m < 5; m++) att[(size_t)n * 160 + gg * 5 + m] = acc[m] * inv;
    att0[(size_t)n * 32 + gg] = acc0 * inv;
  }
}

// ---------------------------------------------------------------------------
// Kernel 4b (fallback): recompute v branch, atomic scatter
// ---------------------------------------------------------------------------
__global__ __launch_bounds__(256) void edgeB_rec(
    const unsigned short* __restrict__ kvmixNb, const float* __restrict__ kv0N,
    const float* __restrict__ Rw, const int* __restrict__ edge,
    const unsigned short* __restrict__ w_chunk, int e0,
    const float* __restrict__ logits, const unsigned* __restrict__ mx,
    const float* __restrict__ den,
    float* __restrict__ att, float* __restrict__ att0, int E) {
  const int g = threadIdx.x & 63;
  const int e = e0 + blockIdx.x * 4 + (threadIdx.x >> 6);
  const int src = edge[e], dst = edge[E + e];
  const int l = g & 1;
  const int h = (g < 32) ? (g >> 2) : ((g - 32) >> 2);
  float m_ = decf(mx[dst * 8 + h]);
  float alpha = __expf(logits[(size_t)e * 8 + h] - m_) / den[dst * 8 + h];
  const unsigned short* wa = w_chunk + (size_t)(e - e0) * 384;
  if (g < 32) {
    const float* rb = Rw + (size_t)e * 50 + l * 25;
    float R[5][5];
#pragma unroll
    for (int a = 0; a < 5; a++)
#pragma unroll
      for (int b = 0; b < 5; b++) R[a][b] = rb[a * 5 + b];
    float xr[5];
    {
      ushort8v xv = *(const ushort8v*)(kvmixNb + (size_t)src * 512 + (32 + g) * 8);
      float x0 = bu2f(xv[0]), x1 = bu2f(xv[1]), x2 = bu2f(xv[2]),
            x3 = bu2f(xv[3]), x4 = bu2f(xv[4]);
#pragma unroll
      for (int m = 0; m < 5; m++)
        xr[m] = R[m][0] * x0 + R[m][1] * x1 + R[m][2] * x2 + R[m][3] * x3 + R[m][4] * x4;
    }
    ushort4 wq = *(const ushort4*)(wa + (32 + g) * 4);
    float w0_ = bu2f(wq.x), w1_ = bu2f(wq.y), w2_ = bu2f(wq.z), w3_ = bu2f(wq.w);
    float wm = bu2f(wa[352 + g]);
    float y[5];
    y[0] = w3_ * xr[4] + w1_ * xr[0];
    y[1] = w2_ * xr[3] + w0_ * xr[1];
    y[2] = wm * xr[2];
    y[3] = w0_ * xr[3] - w2_ * xr[1];
    y[4] = w1_ * xr[4] - w3_ * xr[0];
#pragma unroll
    for (int m = 0; m < 5; m++) {
      float o = R[0][m] * y[0] + R[1][m] * y[1] + R[2][m] * y[2] + R[3][m] * y[3] + R[4][m] * y[4];
      atomicAdd(&att[(size_t)dst * 160 + g * 5 + m], alpha * o);
    }
  } else {
    int j = g - 32;
    float v0 = bu2f(wa[288 + j]) * kv0N[(size_t)src * 64 + 32 + j];
    atomicAdd(&att0[(size_t)dst * 32 + j], alpha * v0);
  }
}

// ---------------------------------------------------------------------------
// Kernel 5: per-node output projection, in place over d_out
// ---------------------------------------------------------------------------
__global__ __launch_bounds__(256) void node_kernel(
    const float* __restrict__ pW, const float* __restrict__ pW0,
    const float* __restrict__ pb0, float* __restrict__ out, int N) {
  __shared__ float sA[4][160];
  __shared__ float sA0[4][32];
  const int tid = threadIdx.x;
  const int wv = tid >> 6, w = tid & 63;
  const int n = blockIdx.x * 4 + wv;
  if (n < N) {
    for (int i = w; i < 160; i += 64) sA[wv][i] = out[(size_t)n * 160 + i];
    if (w < 32) sA0[wv][w] = out[(size_t)N * 160 + (size_t)n * 32 + w];
  }
  __syncthreads();
  if (n >= N) return;
  for (int i = w; i < 160; i += 64) {
    int o = i / 10, lm = i % 10, l = lm / 5, m = lm % 5;
    float a = 0.f;
    const float* wr = pW + l * 256 + o * 16;
#pragma unroll
    for (int c = 0; c < 16; c++) a += wr[c] * sA[wv][c * 10 + l * 5 + m];
    out[(size_t)n * 160 + i] = a;
  }
  if (w < 32) {
    float a = pb0[w];
    const float* wr = pW0 + w * 32;
#pragma unroll
    for (int c = 0; c < 32; c++) a += wr[c] * sA0[wv][c];
    out[(size_t)N * 160 + (size_t)n * 32 + w] = a;
  }
}

// ---------------------------------------------------------------------------
extern "C" void kernel_launch(void* const* d_in, const int* in_sizes, int n_in,
                              void* d_out, int out_size, void* d_ws, size_t ws_size,
                              hipStream_t stream) {
  const float* x_src  = (const float*)d_in[0];
  const float* x_tar  = (const float*)d_in[1];
  const float* x_src0 = (const float*)d_in[2];
  const float* x_tar0 = (const float*)d_in[3];
  const float* Rw     = (const float*)d_in[4];
  const float* ef     = (const float*)d_in[5];
  const int*   edge   = (const int*)d_in[6];
  const float* r_W1 = (const float*)d_in[10];
  const float* r_b1 = (const float*)d_in[11];
  const float* r_g1 = (const float*)d_in[12];
  const float* r_be1 = (const float*)d_in[13];
  const float* r_W2 = (const float*)d_in[14];
  const float* r_b2 = (const float*)d_in[15];
  const float* r_g2 = (const float*)d_in[16];
  const float* r_be2 = (const float*)d_in[17];
  const float* r_W3 = (const float*)d_in[18];
  const float* r_b3 = (const float*)d_in[19];
  const float* qW  = (const float*)d_in[20];
  const float* qW0 = (const float*)d_in[21];
  const float* qb0 = (const float*)d_in[22];
  const float* kvW  = (const float*)d_in[23];
  const float* kvW0 = (const float*)d_in[24];
  const float* kvb0 = (const float*)d_in[25];
  const float* qng  = (const float*)d_in[26];
  const float* qng0 = (const float*)d_in[27];
  const float* kng  = (const float*)d_in[28];
  const float* kng0 = (const float*)d_in[29];
  const float* pW  = (const float*)d_in[30];
  const float* pW0 = (const float*)d_in[31];
  const float* pb0 = (const float*)d_in[32];

  const int N = in_sizes[0] / 160;   // 10000
  const int E = in_sizes[4] / 50;    // 160000
  float* out = (float*)d_out;

  char* ws = (char*)d_ws;
  size_t off = 0;
  auto alloc = [&](size_t bytes) {
    void* p = ws + off;
    off += (bytes + 255) & ~(size_t)255;
    return p;
  };
  unsigned short* W1T = (unsigned short*)alloc(128 * 32 * 2);
  unsigned short* W2T = (unsigned short*)alloc(128 * 128 * 2);
  unsigned short* W3T = (unsigned short*)alloc(384 * 128 * 2);
  float* logits = (float*)alloc((size_t)E * 8 * 4);
  int* rowstart = (int*)alloc((size_t)(N + 1) * 4);
  int* csr      = (int*)alloc((size_t)E * 4);
  size_t zoff = off;
  int* cnt    = (int*)alloc((size_t)N * 4);
  int* cursor = (int*)alloc((size_t)N * 4);
  unsigned* mxb = (unsigned*)alloc((size_t)N * 8 * 4);
  float* den = (float*)alloc((size_t)N * 8 * 4);
  size_t zend = off;
  unsigned short* qmixNb  = (unsigned short*)alloc((size_t)N * 256 * 2);
  float* q0N    = (float*)alloc((size_t)N * 32 * 4);
  unsigned short* kvmixNb = (unsigned short*)alloc((size_t)N * 512 * 2);
  float* kv0N   = (float*)alloc((size_t)N * 64 * 4);

  // per-edge chunk bytes: w_chunk (768) only — h1/h2 live in LDS
  if (ws_size <= off + 256 * 768) return;
  size_t avail = ws_size - off;
  const size_t vsz = (size_t)E * 256 * 2 + (size_t)E * 32 * 2 + 512;
  bool fast = false;
  size_t CE;
  __hip_bfloat16 *vb = nullptr, *v0b = nullptr;
  if (avail >= vsz + (size_t)1024 * 768) {
    fast = true;
    vb  = (__hip_bfloat16*)alloc((size_t)E * 256 * 2);
    v0b = (__hip_bfloat16*)alloc((size_t)E * 32 * 2);
    CE = (ws_size - off) / 768;
  } else {
    CE = avail / 768;
  }
  if (CE > (size_t)E) CE = E;
  CE &= ~(size_t)255;
  if (CE == 0) return;
  unsigned short* w_chunk = (unsigned short*)(ws + off);

  hipMemsetAsync(ws + zoff, 0, zend - zoff, stream);
  hipMemsetAsync(d_out, 0, (size_t)out_size * 4, stream);

  prep_kernel<<<(69632 + 255) / 256, 256, 0, stream>>>(r_W1, r_W2, r_W3, W1T, W2T, W3T);
  nodeprep_kernel<<<(N + 3) / 4, 256, 0, stream>>>(
      x_tar, x_tar0, x_src, x_src0, qW, qW0, qb0, qng0, kvW, kvW0, kvb0,
      qmixNb, q0N, kvmixNb, kv0N, N);
  count_kernel<<<(E + 255) / 256, 256, 0, stream>>>(edge, cnt, E);
  scan_kernel<<<1, 1024, 0, stream>>>(cnt, rowstart, N);
  fill_kernel<<<(E + 255) / 256, 256, 0, stream>>>(edge, rowstart, cursor, csr, E);

  for (int e0 = 0; e0 < E; e0 += (int)CE) {
    int cnt_ = E - e0 < (int)CE ? E - e0 : (int)CE;
    radial_fused<<<(cnt_ + 255) / 256, 256, 0, stream>>>(
        ef, W1T, W2T, W3T, r_b1, r_g1, r_be1, r_b2, r_g2, r_be2, r_b3, w_chunk, e0);
    if (fast)
      edgeA_kernel<1><<<cnt_ / 4, 256, 0, stream>>>(qmixNb, q0N, kvmixNb, kv0N, Rw, edge,
                                                    w_chunk, e0, qng, kng, kng0,
                                                    vb, v0b, logits, mxb, E);
    else
      edgeA_kernel<0><<<cnt_ / 4, 256, 0, stream>>>(qmixNb, q0N, kvmixNb, kv0N, Rw, edge,
                                                    w_chunk, e0, qng, kng, kng0,
                                                    vb, v0b, logits, mxb, E);
  }
  float* att  = out;
  float* att0 = out + (size_t)N * 160;
  if (fast) {
    nodegather_kernel<<<(N + 3) / 4, 256, 0, stream>>>(Rw, csr, rowstart, vb, v0b,
                                                       logits, att, att0, N);
  } else {
    edge2_kernel<<<(E * 8 + 255) / 256, 256, 0, stream>>>(edge, logits, mxb, den, E);
    for (int e0 = 0; e0 < E; e0 += (int)CE) {
      int cnt_ = E - e0 < (int)CE ? E - e0 : (int)CE;
      radial_fused<<<(cnt_ + 255) / 256, 256, 0, stream>>>(
          ef, W1T, W2T, W3T, r_b1, r_g1, r_be1, r_b2, r_g2, r_be2, r_b3, w_chunk, e0);
      edgeB_rec<<<cnt_ / 4, 256, 0, stream>>>(kvmixNb, kv0N, Rw, edge, w_chunk, e0,
                                              logits, mxb, den, att, att0, E);
    }
  }
  node_kernel<<<(N + 3) / 4, 256, 0, stream>>>(pW, pW0, pb0, out, N);
}

// Round 16
// 323.966 us; speedup vs baseline: 1.2312x; 1.0442x over previous
//
#include <hip/hip_runtime.h>
#include <hip/hip_bf16.h>
#include <math.h>

// N=10000, E=160000, C=16, C0=32, L=2, M=5, H=8, R_IN=32, R_HID=128, REQ=384

typedef short bf16x8 __attribute__((ext_vector_type(8)));
typedef float f32x4 __attribute__((ext_vector_type(4)));
typedef unsigned short ushort8v __attribute__((ext_vector_type(8)));

__device__ __forceinline__ float waveSum(float v) {
#pragma unroll
  for (int m = 1; m < 64; m <<= 1) v += __shfl_xor(v, m, 64);
  return v;
}
__device__ __forceinline__ unsigned encf(float f) {
  unsigned u = __float_as_uint(f);
  return (u & 0x80000000u) ? ~u : (u | 0x80000000u);
}
__device__ __forceinline__ float decf(unsigned u) {
  return (u & 0x80000000u) ? __uint_as_float(u & 0x7FFFFFFFu) : __uint_as_float(~u);
}
__device__ __forceinline__ unsigned short f2bu(float f) {
  __hip_bfloat16 h = __float2bfloat16(f);
  unsigned short u;
  __builtin_memcpy(&u, &h, 2);
  return u;
}
__device__ __forceinline__ float bu2f(unsigned u16) {
  unsigned x = u16 << 16;
  float f;
  __builtin_memcpy(&f, &x, 4);
  return f;
}

// ---------------------------------------------------------------------------
// Prep: transpose radial weights to bf16 [n][k] layout
// ---------------------------------------------------------------------------
__global__ __launch_bounds__(256) void prep_kernel(
    const float* __restrict__ W1, const float* __restrict__ W2,
    const float* __restrict__ W3,
    unsigned short* __restrict__ W1T, unsigned short* __restrict__ W2T,
    unsigned short* __restrict__ W3T) {
  int idx = blockIdx.x * 256 + threadIdx.x;
  if (idx < 128 * 32) {
    int n = idx >> 5, k = idx & 31;
    W1T[idx] = f2bu(W1[k * 128 + n]);
  }
  int i2 = idx - 128 * 32;
  if (i2 >= 0 && i2 < 128 * 128) {
    int n = i2 >> 7, k = i2 & 127;
    W2T[i2] = f2bu(W2[k * 128 + n]);
  }
  int i3 = idx - 128 * 32 - 128 * 128;
  if (i3 >= 0 && i3 < 384 * 128) {
    int n = i3 >> 7, k = i3 & 127;
    W3T[i3] = f2bu(W3[k * 384 + n]);
  }
}

// ---------------------------------------------------------------------------
// CSR build: count, scan (1 block), fill
// ---------------------------------------------------------------------------
__global__ __launch_bounds__(256) void count_kernel(const int* __restrict__ edge,
                                                    int* __restrict__ cnt, int E) {
  int e = blockIdx.x * 256 + threadIdx.x;
  if (e < E) atomicAdd(&cnt[edge[E + e]], 1);
}

__global__ __launch_bounds__(1024) void scan_kernel(const int* __restrict__ cnt,
                                                    int* __restrict__ rowstart, int N) {
  __shared__ int sp[1024];
  const int t = threadIdx.x;
  const int chunk = (N + 1023) >> 10;
  const int beg = t * chunk;
  const int end = min(beg + chunk, N);
  int s = 0;
  for (int i = beg; i < end; i++) s += cnt[i];
  sp[t] = s;
  __syncthreads();
  for (int off = 1; off < 1024; off <<= 1) {
    int tmp = (t >= off) ? sp[t - off] : 0;
    __syncthreads();
    sp[t] += tmp;
    __syncthreads();
  }
  int excl = sp[t] - s;
  int run = excl;
  for (int i = beg; i < end; i++) { rowstart[i] = run; run += cnt[i]; }
  if (t == 0) rowstart[N] = sp[1023];
}

__global__ __launch_bounds__(256) void fill_kernel(const int* __restrict__ edge,
                                                   const int* __restrict__ rowstart,
                                                   int* __restrict__ cursor,
                                                   int* __restrict__ csr, int E) {
  int e = blockIdx.x * 256 + threadIdx.x;
  if (e < E) {
    int d = edge[E + e];
    int p = atomicAdd(&cursor[d], 1);
    csr[rowstart[d] + p] = e;
  }
}

// ---------------------------------------------------------------------------
// Node prep: hoist channel-mix GEMMs to nodes.  Mixes stored bf16 padded
// [node][group][8] so edgeA's per-lane gather is one aligned 16B load.
// ---------------------------------------------------------------------------
__global__ __launch_bounds__(256) void nodeprep_kernel(
    const float* __restrict__ xt, const float* __restrict__ xt0,
    const float* __restrict__ xs, const float* __restrict__ xs0,
    const float* __restrict__ qW, const float* __restrict__ qW0,
    const float* __restrict__ qb0, const float* __restrict__ qng0,
    const float* __restrict__ kvW, const float* __restrict__ kvW0,
    const float* __restrict__ kvb0,
    unsigned short* __restrict__ qmixNb, float* __restrict__ q0N,
    unsigned short* __restrict__ kvmixNb, float* __restrict__ kv0N, int N) {
  __shared__ float sXT[4][160];
  __shared__ float sXS[4][160];
  __shared__ float sX0T[4][32];
  __shared__ float sX0S[4][32];
  const int tid = threadIdx.x, wv = tid >> 6, w = tid & 63;
  const int n = blockIdx.x * 4 + wv;
  if (n < N) {
    for (int i = w; i < 160; i += 64) {
      sXT[wv][i] = xt[(size_t)n * 160 + i];
      sXS[wv][i] = xs[(size_t)n * 160 + i];
    }
    if (w < 32) { sX0T[wv][w] = xt0[n * 32 + w]; sX0S[wv][w] = xs0[n * 32 + w]; }
  }
  __syncthreads();
  if (n >= N) return;
  for (int i = w; i < 160; i += 64) {
    int o = i / 10, lm = i % 10, l = lm / 5, m = lm % 5;
    const float4* wr = (const float4*)(qW + l * 256 + o * 16);
    float a = 0.f;
#pragma unroll
    for (int c4 = 0; c4 < 4; c4++) {
      float4 ww = wr[c4];
      a += ww.x * sXT[wv][(c4 * 4 + 0) * 10 + lm] + ww.y * sXT[wv][(c4 * 4 + 1) * 10 + lm]
         + ww.z * sXT[wv][(c4 * 4 + 2) * 10 + lm] + ww.w * sXT[wv][(c4 * 4 + 3) * 10 + lm];
    }
    qmixNb[(size_t)n * 256 + (o * 2 + l) * 8 + m] = f2bu(a);
  }
  for (int i = w; i < 320; i += 64) {
    int o = i / 10, lm = i % 10, l = lm / 5, m = lm % 5;
    const float4* wr = (const float4*)(kvW + l * 512 + o * 16);
    float a = 0.f;
#pragma unroll
    for (int c4 = 0; c4 < 4; c4++) {
      float4 ww = wr[c4];
      a += ww.x * sXS[wv][(c4 * 4 + 0) * 10 + lm] + ww.y * sXS[wv][(c4 * 4 + 1) * 10 + lm]
         + ww.z * sXS[wv][(c4 * 4 + 2) * 10 + lm] + ww.w * sXS[wv][(c4 * 4 + 3) * 10 + lm];
    }
    kvmixNb[(size_t)n * 512 + (o * 2 + l) * 8 + m] = f2bu(a);
  }
  {
    float a = 0.f;
    if (w < 32) {
      a = qb0[w];
      const float4* wr = (const float4*)(qW0 + w * 32);
#pragma unroll
      for (int c4 = 0; c4 < 8; c4++) {
        float4 ww = wr[c4];
        a += ww.x * sX0T[wv][c4 * 4] + ww.y * sX0T[wv][c4 * 4 + 1]
           + ww.z * sX0T[wv][c4 * 4 + 2] + ww.w * sX0T[wv][c4 * 4 + 3];
      }
    }
    float vv = (w < 32) ? a : 0.f;
    float s1 = waveSum(vv), s2 = waveSum(vv * vv);
    float mu = s1 / 32.f, var = s2 / 32.f - mu * mu;
    if (w < 32) q0N[(size_t)n * 32 + w] = (a - mu) * rsqrtf(var + 1e-5f) * qng0[w];
  }
  {
    float a = kvb0[w];
    const float4* wr = (const float4*)(kvW0 + w * 32);
#pragma unroll
    for (int c4 = 0; c4 < 8; c4++) {
      float4 ww = wr[c4];
      a += ww.x * sX0S[wv][c4 * 4] + ww.y * sX0S[wv][c4 * 4 + 1]
         + ww.z * sX0S[wv][c4 * 4 + 2] + ww.w * sX0S[wv][c4 * 4 + 3];
    }
    kv0N[(size_t)n * 64 + w] = a;
  }
}

// ---------------------------------------------------------------------------
// Fused radial MLP (r13/r15-verified config): zero barriers, 64 edges/WAVE,
// 256 edges/block, launch_bounds(256,2) -> 128 VGPR, NO spill.
// LDS 64KB wave-private; L1/L2 ks-outer, L3 jt-outer; LDS-staged stores.
// ---------------------------------------------------------------------------
__global__ __launch_bounds__(256, 2) void radial_fused(
    const float* __restrict__ ef,
    const unsigned short* __restrict__ W1T, const unsigned short* __restrict__ W2T,
    const unsigned short* __restrict__ W3T,
    const float* __restrict__ b1, const float* __restrict__ g1, const float* __restrict__ be1,
    const float* __restrict__ b2, const float* __restrict__ g2, const float* __restrict__ be2,
    const float* __restrict__ b3,
    unsigned short* __restrict__ w_chunk, int e0) {
  __shared__ unsigned short sH[256 * 128];  // 64KB
  const int lane = threadIdx.x & 63;
  const int wid = threadIdx.x >> 6;
  const int colq = lane & 15, rowq = lane >> 4;
  int el[4], eg[4];
  unsigned swz[4], rbase[4];
#pragma unroll
  for (int t = 0; t < 4; t++) {
    el[t] = wid * 64 + t * 16 + colq;
    eg[t] = blockIdx.x * 256 + el[t];
    swz[t] = (unsigned)(el[t] & 7) << 4;
    rbase[t] = (unsigned)el[t] * 256;
  }
  char* sB = (char*)sH;
  f32x4 zz = {0.f, 0.f, 0.f, 0.f};

  // ---- layer 1: 32 -> 128 ----
  bf16x8 bfr[4];
#pragma unroll
  for (int t = 0; t < 4; t++) {
    const float* p = ef + (size_t)(e0 + eg[t]) * 32 + rowq * 8;
    float4 a = *(const float4*)p, b = *(const float4*)(p + 4);
    bfr[t][0] = (short)f2bu(a.x); bfr[t][1] = (short)f2bu(a.y);
    bfr[t][2] = (short)f2bu(a.z); bfr[t][3] = (short)f2bu(a.w);
    bfr[t][4] = (short)f2bu(b.x); bfr[t][5] = (short)f2bu(b.y);
    bfr[t][6] = (short)f2bu(b.z); bfr[t][7] = (short)f2bu(b.w);
  }
  f32x4 acc[4][8];
#pragma unroll
  for (int jt = 0; jt < 8; jt++) {
    bf16x8 wl = *(const bf16x8*)(W1T + (jt * 16 + colq) * 32 + rowq * 8);
#pragma unroll
    for (int t = 0; t < 4; t++)
      acc[t][jt] = __builtin_amdgcn_mfma_f32_16x16x32_bf16(wl, bfr[t], zz, 0, 0, 0);
  }
#pragma unroll
  for (int t = 0; t < 4; t++) {
    float s1 = 0.f, s2 = 0.f;
    float vv[8][4];
#pragma unroll
    for (int jt = 0; jt < 8; jt++) {
      float4 bb = *(const float4*)(b1 + jt * 16 + rowq * 4);
#pragma unroll
      for (int r = 0; r < 4; r++) {
        float v = acc[t][jt][r] + ((const float*)&bb)[r];
        vv[jt][r] = v; s1 += v; s2 += v * v;
      }
    }
    s1 += __shfl_xor(s1, 16, 64); s2 += __shfl_xor(s2, 16, 64);
    s1 += __shfl_xor(s1, 32, 64); s2 += __shfl_xor(s2, 32, 64);
    float mu = s1 * (1.f / 128.f);
    float rs = rsqrtf(s2 * (1.f / 128.f) - mu * mu + 1e-5f);
#pragma unroll
    for (int jt = 0; jt < 8; jt++) {
      float4 gg = *(const float4*)(g1 + jt * 16 + rowq * 4);
      float4 ee = *(const float4*)(be1 + jt * 16 + rowq * 4);
      ushort4 pk;
      unsigned short* pp = &pk.x;
#pragma unroll
      for (int r = 0; r < 4; r++) {
        float v = (vv[jt][r] - mu) * rs * ((const float*)&gg)[r] + ((const float*)&ee)[r];
        v = v / (1.f + __expf(-v));
        pp[r] = f2bu(v);
      }
      *(ushort4*)(sB + rbase[t] + (((unsigned)(jt * 32 + rowq * 8)) ^ swz[t])) = pk;
    }
  }

  // ---- layer 2: 128 -> 128 (ks-outer: one weight fragment feeds 4 MFMAs) ----
#pragma unroll
  for (int t = 0; t < 4; t++)
#pragma unroll
    for (int jt = 0; jt < 8; jt++) acc[t][jt] = zz;
#pragma unroll
  for (int ks = 0; ks < 4; ks++) {
    bf16x8 hh[4];
#pragma unroll
    for (int t = 0; t < 4; t++)
      hh[t] = *(const bf16x8*)(sB + rbase[t] + (((unsigned)(ks * 64 + rowq * 16)) ^ swz[t]));
#pragma unroll
    for (int jt = 0; jt < 8; jt++) {
      bf16x8 wf = *(const bf16x8*)(W2T + (size_t)(jt * 16 + colq) * 128 + ks * 32 + rowq * 8);
#pragma unroll
      for (int t = 0; t < 4; t++)
        acc[t][jt] = __builtin_amdgcn_mfma_f32_16x16x32_bf16(wf, hh[t], acc[t][jt], 0, 0, 0);
    }
  }
#pragma unroll
  for (int t = 0; t < 4; t++) {
    float s1 = 0.f, s2 = 0.f;
    float vv[8][4];
#pragma unroll
    for (int jt = 0; jt < 8; jt++) {
      float4 bb = *(const float4*)(b2 + jt * 16 + rowq * 4);
#pragma unroll
      for (int r = 0; r < 4; r++) {
        float v = acc[t][jt][r] + ((const float*)&bb)[r];
        vv[jt][r] = v; s1 += v; s2 += v * v;
      }
    }
    s1 += __shfl_xor(s1, 16, 64); s2 += __shfl_xor(s2, 16, 64);
    s1 += __shfl_xor(s1, 32, 64); s2 += __shfl_xor(s2, 32, 64);
    float mu = s1 * (1.f / 128.f);
    float rs = rsqrtf(s2 * (1.f / 128.f) - mu * mu + 1e-5f);
#pragma unroll
    for (int jt = 0; jt < 8; jt++) {
      float4 gg = *(const float4*)(g2 + jt * 16 + rowq * 4);
      float4 ee = *(const float4*)(be2 + jt * 16 + rowq * 4);
      ushort4 pk;
      unsigned short* pp = &pk.x;
#pragma unroll
      for (int r = 0; r < 4; r++) {
        float v = (vv[jt][r] - mu) * rs * ((const float*)&gg)[r] + ((const float*)&ee)[r];
        v = v / (1.f + __expf(-v));
        pp[r] = f2bu(v);
      }
      *(ushort4*)(sB + rbase[t] + (((unsigned)(jt * 32 + rowq * 8)) ^ swz[t])) = pk;
    }
  }

  // ---- layer 3: 128 -> 384 (jt-outer), LDS-staged coalesced output ----
  bf16x8 hf[4][4];
#pragma unroll
  for (int t = 0; t < 4; t++)
#pragma unroll
    for (int ks = 0; ks < 4; ks++)
      hf[t][ks] = *(const bf16x8*)(sB + rbase[t] + (((unsigned)(ks * 64 + rowq * 16)) ^ swz[t]));
  const int lq = lane & 15;
  const int eq = lane >> 4;
  for (int cc = 0; cc < 3; cc++) {
#pragma unroll
    for (int jj = 0; jj < 8; jj++) {
      int jt = cc * 8 + jj;
      bf16x8 wf[4];
#pragma unroll
      for (int ks = 0; ks < 4; ks++)
        wf[ks] = *(const bf16x8*)(W3T + (size_t)(jt * 16 + colq) * 128 + ks * 32 + rowq * 8);
      f32x4 a[4] = {zz, zz, zz, zz};
#pragma unroll
      for (int ks = 0; ks < 4; ks++)
#pragma unroll
        for (int t = 0; t < 4; t++)
          a[t] = __builtin_amdgcn_mfma_f32_16x16x32_bf16(wf[ks], hf[t][ks], a[t], 0, 0, 0);
      float4 bb = *(const float4*)(b3 + jt * 16 + rowq * 4);
#pragma unroll
      for (int t = 0; t < 4; t++) {
        ushort4 pk;
        unsigned short* pp = &pk.x;
#pragma unroll
        for (int r = 0; r < 4; r++) pp[r] = f2bu(a[t][r] + ((const float*)&bb)[r]);
        *(ushort4*)(sB + rbase[t] + (((unsigned)(jj * 32 + rowq * 8)) ^ swz[t])) = pk;
      }
    }
    // drain: 16 store instrs, each = 4 contiguous 256B segments (full lines)
#pragma unroll
    for (int i = 0; i < 16; i++) {
      int e2 = wid * 64 + i * 4 + eq;
      unsigned lo2 = ((unsigned)lq * 16) ^ ((unsigned)(e2 & 7) << 4);
      uint4 v = *(const uint4*)(sB + (unsigned)e2 * 256 + lo2);
      size_t gb = (size_t)(blockIdx.x * 256 + e2) * 768 + cc * 256 + lq * 16;
      *(uint4*)((char*)w_chunk + gb) = v;
    }
  }
}

// ---------------------------------------------------------------------------
// Kernel 2: per-edge rotate+conv+norm+logits, REGISTER-ONLY (bf16 mixes).
// ---------------------------------------------------------------------------
template <int STOREV>
__global__ __launch_bounds__(256) void edgeA_kernel(
    const unsigned short* __restrict__ qmixNb, const float* __restrict__ q0N,
    const unsigned short* __restrict__ kvmixNb, const float* __restrict__ kv0N,
    const float* __restrict__ Rw, const int* __restrict__ edge,
    const unsigned short* __restrict__ w_chunk, int e0,
    const float* __restrict__ qng, const float* __restrict__ kng,
    const float* __restrict__ kng0,
    __hip_bfloat16* __restrict__ v_buf, __hip_bfloat16* __restrict__ v0_buf,
    float* __restrict__ logits, unsigned* __restrict__ mx, int E) {
  const int g = threadIdx.x & 63;
  const int e = e0 + blockIdx.x * 4 + (threadIdx.x >> 6);
  const int src = edge[e], dst = edge[E + e];
  const int l = g & 1, cg = g >> 1;

  float R[5][5];
  {
    const float* rb = Rw + (size_t)e * 50 + l * 25;
#pragma unroll
    for (int m = 0; m < 5; m++)
#pragma unroll
      for (int n = 0; n < 5; n++) R[m][n] = rb[m * 5 + n];
  }
  float xr[5];
  {
    ushort8v xv = *(const ushort8v*)(kvmixNb + (size_t)src * 512 + g * 8);
    float x0 = bu2f(xv[0]), x1 = bu2f(xv[1]), x2 = bu2f(xv[2]),
          x3 = bu2f(xv[3]), x4 = bu2f(xv[4]);
#pragma unroll
    for (int m = 0; m < 5; m++)
      xr[m] = R[m][0] * x0 + R[m][1] * x1 + R[m][2] * x2 + R[m][3] * x3 + R[m][4] * x4;
  }
  const unsigned short* wa = w_chunk + (size_t)(e - e0) * 384;
  ushort4 wq = *(const ushort4*)(wa + 4 * g);
  float w0_ = bu2f(wq.x), w1_ = bu2f(wq.y), w2_ = bu2f(wq.z), w3_ = bu2f(wq.w);
  float wm = bu2f(wa[320 + g]);
  float y[5];
  y[0] = w3_ * xr[4] + w1_ * xr[0];
  y[1] = w2_ * xr[3] + w0_ * xr[1];
  y[2] = wm * xr[2];
  y[3] = w0_ * xr[3] - w2_ * xr[1];
  y[4] = w1_ * xr[4] - w3_ * xr[0];
  float y0 = bu2f(wa[256 + g]) * kv0N[(size_t)src * 64 + g];

  float p = 0.f;
  if (g < 32) p = y[0] * y[0] + y[1] * y[1] + y[2] * y[2] + y[3] * y[3] + y[4] * y[4];
  float rmsk = rsqrtf(waveSum(p) * (1.f / 160.f) + 1e-5f);
  float kngc = (g < 32) ? kng[cg] : 0.f;
  float yk[5];
#pragma unroll
  for (int m = 0; m < 5; m++) yk[m] = y[m] * rmsk * kngc;
  float k0v = (g < 32) ? y0 : 0.f;
  float s1 = waveSum(k0v), s2 = waveSum(k0v * k0v);
  float mu = s1 * (1.f / 32.f), var = s2 * (1.f / 32.f) - mu * mu;
  float k0n = (k0v - mu) * rsqrtf(var + 1e-5f) * ((g < 32) ? kng0[g] : 0.f);

  float qn[5];
  float q0 = 0.f;
  {
    float qx0 = 0.f, qx1 = 0.f, qx2 = 0.f, qx3 = 0.f, qx4 = 0.f;
    if (g < 32) {
      ushort8v qv = *(const ushort8v*)(qmixNb + (size_t)dst * 256 + g * 8);
      qx0 = bu2f(qv[0]); qx1 = bu2f(qv[1]); qx2 = bu2f(qv[2]);
      qx3 = bu2f(qv[3]); qx4 = bu2f(qv[4]);
      q0 = q0N[(size_t)dst * 32 + g];
    }
    float qr[5];
#pragma unroll
    for (int m = 0; m < 5; m++)
      qr[m] = R[m][0] * qx0 + R[m][1] * qx1 + R[m][2] * qx2 + R[m][3] * qx3 + R[m][4] * qx4;
    float pq = qr[0] * qr[0] + qr[1] * qr[1] + qr[2] * qr[2] + qr[3] * qr[3] + qr[4] * qr[4];
    float rmsq = rsqrtf(waveSum(pq) * (1.f / 160.f) + 1e-5f);
    float qngc = (g < 32) ? qng[cg] : 0.f;
#pragma unroll
    for (int m = 0; m < 5; m++) qn[m] = qr[m] * rmsq * qngc;
  }

  float part = qn[0] * yk[0] + qn[1] * yk[1] + qn[2] * yk[2] + qn[3] * yk[3] + qn[4] * yk[4]
             + q0 * k0n;
  part += __shfl_xor(part, 1, 64);
  part += __shfl_xor(part, 2, 64);
  if (g < 32 && (g & 3) == 0) {
    int h = g >> 2;
    float lg = part * 0.70710678118654752f;
    logits[(size_t)e * 8 + h] = lg;
    if (!STOREV) atomicMax(&mx[dst * 8 + h], encf(lg));
  }
  if (STOREV && g >= 32) {
    int j = g - 32;
    ushort8v pk;
    pk[0] = f2bu(y[0]); pk[1] = f2bu(y[1]); pk[2] = f2bu(y[2]);
    pk[3] = f2bu(y[3]); pk[4] = f2bu(y[4]); pk[5] = 0; pk[6] = 0; pk[7] = 0;
    *(ushort8v*)((char*)v_buf + ((size_t)e * 256 + j * 8) * 2) = pk;
    v0_buf[(size_t)e * 32 + j] = __float2bfloat16(y0);
  }
}

// ---------------------------------------------------------------------------
// Kernel 3 (fallback only): denominator
// ---------------------------------------------------------------------------
__global__ __launch_bounds__(256) void edge2_kernel(
    const int* __restrict__ edge, const float* __restrict__ logits,
    const unsigned* __restrict__ mx, float* __restrict__ den, int E) {
  int idx = blockIdx.x * 256 + threadIdx.x;
  if (idx >= E * 8) return;
  int e = idx >> 3, h = idx & 7;
  int dst = edge[E + e];
  float m = decf(mx[dst * 8 + h]);
  atomicAdd(&den[dst * 8 + h], __expf(logits[idx] - m));
}

// ---------------------------------------------------------------------------
// Kernel 4 (fast): per-NODE gather + FUSED output projection.
// Gather (parity-split, fused 2-pass softmax) lands acc in LDS in the
// [c][l][m] layout the projection consumes; one barrier; project; store
// final output directly.  Removes att/att0 global round-trip + node_kernel
// launch + fast-path d_out memset.
// ---------------------------------------------------------------------------
__global__ __launch_bounds__(256) void nodegather_kernel(
    const float* __restrict__ Rw, const int* __restrict__ csr,
    const int* __restrict__ rowstart,
    const __hip_bfloat16* __restrict__ v_buf, const __hip_bfloat16* __restrict__ v0_buf,
    const float* __restrict__ logits,
    const float* __restrict__ pW, const float* __restrict__ pW0,
    const float* __restrict__ pb0,
    float* __restrict__ out, int N) {
  __shared__ float sA[4][160];
  __shared__ float sA0[4][32];
  const int g = threadIdx.x & 63;
  const int wv = threadIdx.x >> 6;
  const int n = blockIdx.x * 4 + wv;
  const bool active = (n < N);
  const int ep = g >> 5, gg = g & 31;
  const int l = gg & 1, h = gg >> 2;

  int row = 0, deg = 0;
  if (active) {
    row = rowstart[n];
    deg = rowstart[n + 1] - row;
  }

  float acc[5] = {0.f, 0.f, 0.f, 0.f, 0.f};
  float acc0 = 0.f;
  float inv = 0.f;
  if (active && deg > 0) {
    float mxh = -3.402823466e38f;
    for (int k = ep; k < deg; k += 2)
      mxh = fmaxf(mxh, logits[(size_t)csr[row + k] * 8 + h]);
    mxh = fmaxf(mxh, __shfl_xor(mxh, 32, 64));

    float den = 0.f;
    for (int k = ep; k < deg; k += 2) {
      int e = csr[row + k];
      float ex = __expf(logits[(size_t)e * 8 + h] - mxh);
      den += ex;
      uint4 vvv = *(const uint4*)((const char*)v_buf + ((size_t)e * 256 + gg * 8) * 2);
      float v0_ = bu2f(vvv.x & 0xffffu), v1_ = bu2f(vvv.x >> 16);
      float v2_ = bu2f(vvv.y & 0xffffu), v3_ = bu2f(vvv.y >> 16);
      float v4_ = bu2f(vvv.z & 0xffffu);
      const float* rb = Rw + (size_t)e * 50 + l * 25;
#pragma unroll
      for (int m = 0; m < 5; m++) {
        float o = rb[m] * v0_ + rb[5 + m] * v1_ + rb[10 + m] * v2_ +
                  rb[15 + m] * v3_ + rb[20 + m] * v4_;
        acc[m] += ex * o;
      }
      acc0 += ex * __bfloat162float(v0_buf[(size_t)e * 32 + gg]);
    }
    den += __shfl_xor(den, 32, 64);
#pragma unroll
    for (int m = 0; m < 5; m++) acc[m] += __shfl_xor(acc[m], 32, 64);
    acc0 += __shfl_xor(acc0, 32, 64);
    inv = 1.f / den;
  }
  if (active && g < 32) {
#pragma unroll
    for (int m = 0; m < 5; m++) sA[wv][gg * 5 + m] = acc[m] * inv;
    sA0[wv][gg] = acc0 * inv;
  }
  __syncthreads();
  if (!active) return;

  // ---- fused output projection (reads LDS, writes final out) ----
  for (int i = g; i < 160; i += 64) {
    int o = i / 10, lm = i % 10, l2 = lm / 5, m = lm % 5;
    float a = 0.f;
    const float* wr = pW + l2 * 256 + o * 16;
#pragma unroll
    for (int c = 0; c < 16; c++) a += wr[c] * sA[wv][c * 10 + l2 * 5 + m];
    out[(size_t)n * 160 + i] = a;
  }
  if (g < 32) {
    float a = pb0[g];
    const float* wr = pW0 + g * 32;
#pragma unroll
    for (int c = 0; c < 32; c++) a += wr[c] * sA0[wv][c];
    out[(size_t)N * 160 + (size_t)n * 32 + g] = a;
  }
}

// ---------------------------------------------------------------------------
// Kernel 4b (fallback): recompute v branch, atomic scatter
// ---------------------------------------------------------------------------
__global__ __launch_bounds__(256) void edgeB_rec(
    const unsigned short* __restrict__ kvmixNb, const float* __restrict__ kv0N,
    const float* __restrict__ Rw, const int* __restrict__ edge,
    const unsigned short* __restrict__ w_chunk, int e0,
    const float* __restrict__ logits, const unsigned* __restrict__ mx,
    const float* __restrict__ den,
    float* __restrict__ att, float* __restrict__ att0, int E) {
  const int g = threadIdx.x & 63;
  const int e = e0 + blockIdx.x * 4 + (threadIdx.x >> 6);
  const int src = edge[e], dst = edge[E + e];
  const int l = g & 1;
  const int h = (g < 32) ? (g >> 2) : ((g - 32) >> 2);
  float m_ = decf(mx[dst * 8 + h]);
  float alpha = __expf(logits[(size_t)e * 8 + h] - m_) / den[dst * 8 + h];
  const unsigned short* wa = w_chunk + (size_t)(e - e0) * 384;
  if (g < 32) {
    const float* rb = Rw + (size_t)e * 50 + l * 25;
    float R[5][5];
#pragma unroll
    for (int a = 0; a < 5; a++)
#pragma unroll
      for (int b = 0; b < 5; b++) R[a][b] = rb[a * 5 + b];
    float xr[5];
    {
      ushort8v xv = *(const ushort8v*)(kvmixNb + (size_t)src * 512 + (32 + g) * 8);
      float x0 = bu2f(xv[0]), x1 = bu2f(xv[1]), x2 = bu2f(xv[2]),
            x3 = bu2f(xv[3]), x4 = bu2f(xv[4]);
#pragma unroll
      for (int m = 0; m < 5; m++)
        xr[m] = R[m][0] * x0 + R[m][1] * x1 + R[m][2] * x2 + R[m][3] * x3 + R[m][4] * x4;
    }
    ushort4 wq = *(const ushort4*)(wa + (32 + g) * 4);
    float w0_ = bu2f(wq.x), w1_ = bu2f(wq.y), w2_ = bu2f(wq.z), w3_ = bu2f(wq.w);
    float wm = bu2f(wa[352 + g]);
    float y[5];
    y[0] = w3_ * xr[4] + w1_ * xr[0];
    y[1] = w2_ * xr[3] + w0_ * xr[1];
    y[2] = wm * xr[2];
    y[3] = w0_ * xr[3] - w2_ * xr[1];
    y[4] = w1_ * xr[4] - w3_ * xr[0];
#pragma unroll
    for (int m = 0; m < 5; m++) {
      float o = R[0][m] * y[0] + R[1][m] * y[1] + R[2][m] * y[2] + R[3][m] * y[3] + R[4][m] * y[4];
      atomicAdd(&att[(size_t)dst * 160 + g * 5 + m], alpha * o);
    }
  } else {
    int j = g - 32;
    float v0 = bu2f(wa[288 + j]) * kv0N[(size_t)src * 64 + 32 + j];
    atomicAdd(&att0[(size_t)dst * 32 + j], alpha * v0);
  }
}

// ---------------------------------------------------------------------------
// Kernel 5 (fallback only): per-node output projection, in place over d_out
// ---------------------------------------------------------------------------
__global__ __launch_bounds__(256) void node_kernel(
    const float* __restrict__ pW, const float* __restrict__ pW0,
    const float* __restrict__ pb0, float* __restrict__ out, int N) {
  __shared__ float sA[4][160];
  __shared__ float sA0[4][32];
  const int tid = threadIdx.x;
  const int wv = tid >> 6, w = tid & 63;
  const int n = blockIdx.x * 4 + wv;
  if (n < N) {
    for (int i = w; i < 160; i += 64) sA[wv][i] = out[(size_t)n * 160 + i];
    if (w < 32) sA0[wv][w] = out[(size_t)N * 160 + (size_t)n * 32 + w];
  }
  __syncthreads();
  if (n >= N) return;
  for (int i = w; i < 160; i += 64) {
    int o = i / 10, lm = i % 10, l = lm / 5, m = lm % 5;
    float a = 0.f;
    const float* wr = pW + l * 256 + o * 16;
#pragma unroll
    for (int c = 0; c < 16; c++) a += wr[c] * sA[wv][c * 10 + l * 5 + m];
    out[(size_t)n * 160 + i] = a;
  }
  if (w < 32) {
    float a = pb0[w];
    const float* wr = pW0 + w * 32;
#pragma unroll
    for (int c = 0; c < 32; c++) a += wr[c] * sA0[wv][c];
    out[(size_t)N * 160 + (size_t)n * 32 + w] = a;
  }
}

// ---------------------------------------------------------------------------
extern "C" void kernel_launch(void* const* d_in, const int* in_sizes, int n_in,
                              void* d_out, int out_size, void* d_ws, size_t ws_size,
                              hipStream_t stream) {
  const float* x_src  = (const float*)d_in[0];
  const float* x_tar  = (const float*)d_in[1];
  const float* x_src0 = (const float*)d_in[2];
  const float* x_tar0 = (const float*)d_in[3];
  const float* Rw     = (const float*)d_in[4];
  const float* ef     = (const float*)d_in[5];
  const int*   edge   = (const int*)d_in[6];
  const float* r_W1 = (const float*)d_in[10];
  const float* r_b1 = (const float*)d_in[11];
  const float* r_g1 = (const float*)d_in[12];
  const float* r_be1 = (const float*)d_in[13];
  const float* r_W2 = (const float*)d_in[14];
  const float* r_b2 = (const float*)d_in[15];
  const float* r_g2 = (const float*)d_in[16];
  const float* r_be2 = (const float*)d_in[17];
  const float* r_W3 = (const float*)d_in[18];
  const float* r_b3 = (const float*)d_in[19];
  const float* qW  = (const float*)d_in[20];
  const float* qW0 = (const float*)d_in[21];
  const float* qb0 = (const float*)d_in[22];
  const float* kvW  = (const float*)d_in[23];
  const float* kvW0 = (const float*)d_in[24];
  const float* kvb0 = (const float*)d_in[25];
  const float* qng  = (const float*)d_in[26];
  const float* qng0 = (const float*)d_in[27];
  const float* kng  = (const float*)d_in[28];
  const float* kng0 = (const float*)d_in[29];
  const float* pW  = (const float*)d_in[30];
  const float* pW0 = (const float*)d_in[31];
  const float* pb0 = (const float*)d_in[32];

  const int N = in_sizes[0] / 160;   // 10000
  const int E = in_sizes[4] / 50;    // 160000
  float* out = (float*)d_out;

  char* ws = (char*)d_ws;
  size_t off = 0;
  auto alloc = [&](size_t bytes) {
    void* p = ws + off;
    off += (bytes + 255) & ~(size_t)255;
    return p;
  };
  unsigned short* W1T = (unsigned short*)alloc(128 * 32 * 2);
  unsigned short* W2T = (unsigned short*)alloc(128 * 128 * 2);
  unsigned short* W3T = (unsigned short*)alloc(384 * 128 * 2);
  float* logits = (float*)alloc((size_t)E * 8 * 4);
  int* rowstart = (int*)alloc((size_t)(N + 1) * 4);
  int* csr      = (int*)alloc((size_t)E * 4);
  size_t zoff = off;
  int* cnt    = (int*)alloc((size_t)N * 4);
  int* cursor = (int*)alloc((size_t)N * 4);
  unsigned* mxb = (unsigned*)alloc((size_t)N * 8 * 4);
  float* den = (float*)alloc((size_t)N * 8 * 4);
  size_t zend = off;
  unsigned short* qmixNb  = (unsigned short*)alloc((size_t)N * 256 * 2);
  float* q0N    = (float*)alloc((size_t)N * 32 * 4);
  unsigned short* kvmixNb = (unsigned short*)alloc((size_t)N * 512 * 2);
  float* kv0N   = (float*)alloc((size_t)N * 64 * 4);

  // per-edge chunk bytes: w_chunk (768) only — h1/h2 live in LDS
  if (ws_size <= off + 256 * 768) return;
  size_t avail = ws_size - off;
  const size_t vsz = (size_t)E * 256 * 2 + (size_t)E * 32 * 2 + 512;
  bool fast = false;
  size_t CE;
  __hip_bfloat16 *vb = nullptr, *v0b = nullptr;
  if (avail >= vsz + (size_t)1024 * 768) {
    fast = true;
    vb  = (__hip_bfloat16*)alloc((size_t)E * 256 * 2);
    v0b = (__hip_bfloat16*)alloc((size_t)E * 32 * 2);
    CE = (ws_size - off) / 768;
  } else {
    CE = avail / 768;
  }
  if (CE > (size_t)E) CE = E;
  CE &= ~(size_t)255;
  if (CE == 0) return;
  unsigned short* w_chunk = (unsigned short*)(ws + off);

  hipMemsetAsync(ws + zoff, 0, zend - zoff, stream);
  if (!fast) hipMemsetAsync(d_out, 0, (size_t)out_size * 4, stream);

  prep_kernel<<<(69632 + 255) / 256, 256, 0, stream>>>(r_W1, r_W2, r_W3, W1T, W2T, W3T);
  nodeprep_kernel<<<(N + 3) / 4, 256, 0, stream>>>(
      x_tar, x_tar0, x_src, x_src0, qW, qW0, qb0, qng0, kvW, kvW0, kvb0,
      qmixNb, q0N, kvmixNb, kv0N, N);
  count_kernel<<<(E + 255) / 256, 256, 0, stream>>>(edge, cnt, E);
  scan_kernel<<<1, 1024, 0, stream>>>(cnt, rowstart, N);
  fill_kernel<<<(E + 255) / 256, 256, 0, stream>>>(edge, rowstart, cursor, csr, E);

  for (int e0 = 0; e0 < E; e0 += (int)CE) {
    int cnt_ = E - e0 < (int)CE ? E - e0 : (int)CE;
    radial_fused<<<(cnt_ + 255) / 256, 256, 0, stream>>>(
        ef, W1T, W2T, W3T, r_b1, r_g1, r_be1, r_b2, r_g2, r_be2, r_b3, w_chunk, e0);
    if (fast)
      edgeA_kernel<1><<<cnt_ / 4, 256, 0, stream>>>(qmixNb, q0N, kvmixNb, kv0N, Rw, edge,
                                                    w_chunk, e0, qng, kng, kng0,
                                                    vb, v0b, logits, mxb, E);
    else
      edgeA_kernel<0><<<cnt_ / 4, 256, 0, stream>>>(qmixNb, q0N, kvmixNb, kv0N, Rw, edge,
                                                    w_chunk, e0, qng, kng, kng0,
                                                    vb, v0b, logits, mxb, E);
  }
  if (fast) {
    nodegather_kernel<<<(N + 3) / 4, 256, 0, stream>>>(Rw, csr, rowstart, vb, v0b,
                                                       logits, pW, pW0, pb0, out, N);
  } else {
    float* att  = out;
    float* att0 = out + (size_t)N * 160;
    edge2_kernel<<<(E * 8 + 255) / 256, 256, 0, stream>>>(edge, logits, mxb, den, E);
    for (int e0 = 0; e0 < E; e0 += (int)CE) {
      int cnt_ = E - e0 < (int)CE ? E - e0 : (int)CE;
      radial_fused<<<(cnt_ + 255) / 256, 256, 0, stream>>>(
          ef, W1T, W2T, W3T, r_b1, r_g1, r_be1, r_b2, r_g2, r_be2, r_b3, w_chunk, e0);
      edgeB_rec<<<cnt_ / 4, 256, 0, stream>>>(kvmixNb, kv0N, Rw, edge, w_chunk, e0,
                                              logits, mxb, den, att, att0, E);
    }
    node_kernel<<<(N + 3) / 4, 256, 0, stream>>>(pW, pW0, pb0, out, N);
  }
}